// Round 10
// baseline (9074.717 us; speedup 1.0000x reference)
//
#include <hip/hip_runtime.h>
#include <hip/hip_bf16.h>

typedef float f32x4 __attribute__((ext_vector_type(4)));
typedef __bf16 bf16x8 __attribute__((ext_vector_type(8)));
typedef short s16x8 __attribute__((ext_vector_type(8)));
typedef unsigned short u16;
typedef unsigned long long u64;
typedef unsigned char u8;

constexpr int Bb = 256, Tt = 128, Ff = 256, Hh = 512;
constexpr int TF = Tt * Ff;                       // 32768
constexpr long OFF_RECON = (long)Bb * Tt * Ff;    // 8388608
constexpr long OFF_H     = 2L * Bb * Tt * Ff;     // 16777216
constexpr long OFF_LOSS  = OFF_H + (long)Bb * Hh; // 16908288

__device__ inline float sigf(float v){ return 1.f / (1.f + expf(-v)); }
__device__ inline u16 f2b(float f){
  unsigned u = __float_as_uint(f);
  u += 0x7fffu + ((u >> 16) & 1u);   // RNE
  return (u16)(u >> 16);
}
__device__ inline float b2f(u16 b){ return __uint_as_float(((unsigned)b) << 16); }

// ---- fp8 e4m3 (OCP) conversion ----
__device__ inline unsigned f2e4_sw(float f){
  unsigned u = __float_as_uint(f);
  unsigned s = (u >> 24) & 0x80u;
  int e = (int)((u >> 23) & 0xff) - 127;
  unsigned m = u & 0x7fffffu;
  if (((u >> 23) & 0xff) == 0xff) return s | 0x7e;
  if (e > 8 || (e == 8 && m > 0x600000)) return s | 0x7e;
  if (e < -10) return s;
  if (e >= -6) {
    unsigned keep = m >> 20, rest = m & 0xfffffu;
    keep += (rest > 0x80000u) || (rest == 0x80000u && (keep & 1));
    unsigned ee = (unsigned)(e + 7);
    if (keep == 8) { keep = 0; ee += 1; }
    if (ee >= 16) return s | 0x7e;
    return s | (ee << 3) | keep;
  }
  unsigned full = (1u << 23) | m;
  int shift = 20 + (-6 - e);
  unsigned keep = full >> shift;
  unsigned rest = full & ((1u << shift) - 1u);
  unsigned half = 1u << (shift - 1);
  keep += (rest > half) || (rest == half && (keep & 1));
  return s | keep;
}
__device__ inline unsigned f2e4(float f){
#if __has_builtin(__builtin_amdgcn_cvt_pk_fp8_f32)
  return (unsigned)__builtin_amdgcn_cvt_pk_fp8_f32(f, f, 0, false) & 0xffu;
#else
  return f2e4_sw(f);
#endif
}
__device__ inline unsigned pk2e4(float a, float b){
#if __has_builtin(__builtin_amdgcn_cvt_pk_fp8_f32)
  return (unsigned)__builtin_amdgcn_cvt_pk_fp8_f32(a, b, 0, false) & 0xffffu;
#else
  return f2e4_sw(a) | (f2e4_sw(b) << 8);
#endif
}
__device__ inline unsigned pk4e4(float a, float b, float c, float d){
#if __has_builtin(__builtin_amdgcn_cvt_pk_fp8_f32)
  int lo = __builtin_amdgcn_cvt_pk_fp8_f32(a, b, 0, false);
  return (unsigned)__builtin_amdgcn_cvt_pk_fp8_f32(c, d, lo & 0xffff, true);
#else
  return f2e4_sw(a) | (f2e4_sw(b)<<8) | (f2e4_sw(c)<<16) | (f2e4_sw(d)<<24);
#endif
}

__device__ inline f32x4 mfma16(bf16x8 a, bf16x8 b, f32x4 c){
  return __builtin_amdgcn_mfma_f32_16x16x32_bf16(a, b, c, 0, 0, 0);
}
__device__ inline f32x4 mfma8(u64 a, u64 b, f32x4 c){
  return __builtin_amdgcn_mfma_f32_16x16x32_fp8_fp8((long)a, (long)b, c, 0, 0, 0);
}
__device__ inline bf16x8 ldb8(const u16* p){ return *reinterpret_cast<const bf16x8*>(p); }
__device__ inline bf16x8 cvt8(const float* p){
  const float4 a = ((const float4*)p)[0], b = ((const float4*)p)[1];
  s16x8 r;
  r[0]=f2b(a.x); r[1]=f2b(a.y); r[2]=f2b(a.z); r[3]=f2b(a.w);
  r[4]=f2b(b.x); r[5]=f2b(b.y); r[6]=f2b(b.z); r[7]=f2b(b.w);
  return __builtin_bit_cast(bf16x8, r);
}

// ---------------- hoisted big GEMMs (gamma_h, beta for all t; [t][b] layout) ----------------
enum { M_GH, M_BETA };

struct P {
  const float *x, *mask, *deltas;
  const float *b_gh, *w_gx, *b_gx, *b_comb;
  const u16 *Wgh, *Wcomb;
  u16 *gammah, *beta;
};

template<int MODE>
__global__ __launch_bounds__(256) void gk(P p)
{
  constexpr int K = (MODE==M_GH) ? 256 : 512;
  const int lane = threadIdx.x & 63;
  const int w = threadIdx.x >> 6;
  const int m0 = blockIdx.y*64 + (w>>1)*32;
  const int n0 = blockIdx.x*64 + (w&1)*32;
  const int fr = lane & 15;
  const int kg = (lane >> 4) << 3;

  f32x4 acc[2][2] = {};
  for (int k = 0; k < K; k += 32) {
    const int kk = k + kg;
    bf16x8 a[2], b[2];
    #pragma unroll
    for (int r = 0; r < 2; ++r) {
      const int mr = m0 + 16*r + fr;
      if constexpr (MODE == M_GH) {
        a[r] = cvt8(p.deltas + (size_t)mr*256 + kk);
      } else {
        if (kk < 256) {
          const float4 d0 = *(const float4*)(p.deltas + (size_t)mr*256 + kk);
          const float4 d1 = *(const float4*)(p.deltas + (size_t)mr*256 + kk + 4);
          const float4 w0 = *(const float4*)(p.w_gx + kk);
          const float4 w1 = *(const float4*)(p.w_gx + kk + 4);
          const float4 g0 = *(const float4*)(p.b_gx + kk);
          const float4 g1 = *(const float4*)(p.b_gx + kk + 4);
          s16x8 v;
          v[0]=f2b(expf(-fmaxf(d0.x*w0.x+g0.x,0.f)));
          v[1]=f2b(expf(-fmaxf(d0.y*w0.y+g0.y,0.f)));
          v[2]=f2b(expf(-fmaxf(d0.z*w0.z+g0.z,0.f)));
          v[3]=f2b(expf(-fmaxf(d0.w*w0.w+g0.w,0.f)));
          v[4]=f2b(expf(-fmaxf(d1.x*w1.x+g1.x,0.f)));
          v[5]=f2b(expf(-fmaxf(d1.y*w1.y+g1.y,0.f)));
          v[6]=f2b(expf(-fmaxf(d1.z*w1.z+g1.z,0.f)));
          v[7]=f2b(expf(-fmaxf(d1.w*w1.w+g1.w,0.f)));
          a[r] = __builtin_bit_cast(bf16x8, v);
        } else {
          a[r] = cvt8(p.mask + (size_t)mr*256 + (kk-256));
        }
      }
    }
    #pragma unroll
    for (int cc = 0; cc < 2; ++cc) {
      const int nr = n0 + 16*cc + fr;
      if constexpr (MODE == M_GH) b[cc] = ldb8(p.Wgh   + (size_t)nr*256 + kk);
      else                        b[cc] = ldb8(p.Wcomb + (size_t)nr*512 + kk);
    }
    #pragma unroll
    for (int r = 0; r < 2; ++r)
      #pragma unroll
      for (int cc = 0; cc < 2; ++cc)
        acc[r][cc] = mfma16(a[r], b[cc], acc[r][cc]);
  }

  #pragma unroll
  for (int r = 0; r < 2; ++r)
    #pragma unroll
    for (int cc = 0; cc < 2; ++cc)
      #pragma unroll
      for (int q = 0; q < 4; ++q) {
        const int m = m0 + 16*r + (lane>>4)*4 + q;   // m = b*128 + t
        const int n = n0 + 16*cc + (lane&15);
        const size_t tb = (size_t)(m & 127)*256 + (m >> 7);   // [t][b]
        if constexpr (MODE == M_GH) {
          float v = expf(-fmaxf(acc[r][cc][q] + p.b_gh[n], 0.f));
          p.gammah[tb*512 + n] = f2b(v);
        } else {
          float v = sigf(acc[r][cc][q] + p.b_comb[n]);
          p.beta[tb*256 + n] = f2b(v);
        }
      }
}

// ---------------- weight conversion / den / final ----------------
constexpr int CV_TOT = 131072+131072+65536+131072; // bf16 ones
__global__ __launch_bounds__(256) void k_conv(
    const float* Wgh, const float* Whist, const float* Wfr, const float* Wcomb,
    u16* ogh, u16* ohist, u16* ofr, u16* ocomb)
{
  int i = blockIdx.x*256 + threadIdx.x;
  if (i >= CV_TOT) return;
  int j = i;
  if (j < 131072) { ogh[j] = f2b(Wgh[j]); return; }       j -= 131072;
  if (j < 131072) { ohist[j] = f2b(Whist[j]); return; }   j -= 131072;
  if (j < 65536)  { ofr[j] = ((j>>8)==(j&255)) ? (u16)0 : f2b(Wfr[j]); return; } j -= 65536;
  ocomb[j] = f2b(Wcomb[j]);
}

__global__ __launch_bounds__(256) void k_conv8(
    const float* Wih, const float* Whh, u8* oih, u8* ohh)
{
  int i = blockIdx.x*256 + threadIdx.x;   // pair index, total 1048576
  if (i < 524288) {
    ((u16*)oih)[i] = (u16)pk2e4(Wih[2*i], Wih[2*i+1]);
  } else {
    int j = i - 524288;
    ((u16*)ohh)[j] = (u16)pk2e4(Whh[2*j], Whh[2*j+1]);
  }
}

__global__ __launch_bounds__(256) void k_den(const float* __restrict__ mask,
                                             float* den, u8* mask8)
{
  const int t = blockIdx.x;
  const int f = threadIdx.x;
  float s = 0.f;
  for (int b = 0; b < Bb; ++b) {
    float mv = mask[(size_t)b*TF + (size_t)t*256 + f];
    s += mv;
    mask8[((size_t)t*256 + b)*256 + f] = (u8)f2e4(mv);
  }
  __shared__ float red[4];
  #pragma unroll
  for (int o = 32; o; o >>= 1) s += __shfl_down(s, o);
  if ((f & 63) == 0) red[f >> 6] = s;
  __syncthreads();
  if (f == 0) den[t] = red[0]+red[1]+red[2]+red[3];
}

__global__ void k_final(const float* num, const float* den, float* out)
{
  if (threadIdx.x < 64) {
    int t = threadIdx.x;
    float s = num[t]/(den[t]+1e-12f) + num[t+64]/(den[t+64]+1e-12f);
    #pragma unroll
    for (int o = 32; o; o >>= 1) s += __shfl_down(s, o);
    if (t == 0) { out[OFF_LOSS] = s; out[OFF_LOSS+1] = 0.f; }
  }
}

// ---------------- single per-step kernel: A (redundant per cg) + B ----------------
struct PS {
  const float *x, *mask;
  const float *b_hist, *b_fr, *b_ih, *b_hh;
  const u16 *Whist, *Wfr, *gammah, *beta;
  const u8 *Wih8, *Whh8, *mask8;
  u16 *hb0, *hb1; u8 *h80, *h81;     // parity double-buffered h (bf16 + fp8)
  float *c, *num, *out;
};

// grid 64: slab = bid&7 (32 rows; same-slab blocks on one XCD via round-robin),
// cg = bid>>3 (64 h-cols). Per-XCD weights 2.4MB < 4MB L2, resident across steps.
__global__ __launch_bounds__(512) void k_step(PS p, int t)
{
  __shared__ char smem[43520];
  float* pre_s  = (float*)smem;           // [4][32][68] f32 (aliases xr_s)
  u16*   xr_s   = (u16*)smem;             // [32][264] bf16
  u8*    ximp_s = (u8*)(smem + 34816);    // [32][272] fp8

  const int tid = threadIdx.x, lane = tid & 63, w = tid >> 6;
  const int fr = lane & 15, kg = (lane >> 4) << 3;
  const int slab = blockIdx.x & 7, cg = blockIdx.x >> 3;
  const int m0 = slab*32, hc0 = cg*64;

  const u16* hr = (t & 1) ? p.hb1 : p.hb0;
  u16*       hw = (t & 1) ? p.hb0 : p.hb1;
  const u8*  h8r = (t & 1) ? p.h81 : p.h80;
  u8*        h8w = (t & 1) ? p.h80 : p.h81;

  // ===== A-part (redundant per cg): XH (K=512) -> xr(LDS) -> XU (K=256) =====
  const int rh = w >> 2, cq = w & 3;
  f32x4 acc[4] = {};
  #pragma unroll
  for (int k = 0; k < 16; ++k) {
    bf16x8 a = ldb8(hr + (size_t)(m0 + rh*16 + fr)*512 + k*32 + kg);
    #pragma unroll
    for (int cc = 0; cc < 4; ++cc)
      acc[cc] = mfma16(a, ldb8(p.Whist + (size_t)(cq*64 + cc*16 + fr)*512 + k*32 + kg), acc[cc]);
  }
  float xhv[16], mmv[16], xxv[16];
  #pragma unroll
  for (int cc = 0; cc < 4; ++cc)
    #pragma unroll
    for (int q = 0; q < 4; ++q) {
      const int e = cc*4 + q;
      const int mi = rh*16 + (lane>>4)*4 + q;
      const int n  = cq*64 + cc*16 + fr;
      const float v = acc[cc][q] + p.b_hist[n];
      xhv[e] = v;
      const size_t gi = (size_t)(m0+mi)*TF + (size_t)t*256 + n;
      mmv[e] = p.mask[gi];
      xxv[e] = p.x[gi];
      xr_s[mi*264 + n] = f2b(mmv[e]*xxv[e] + (1.f-mmv[e])*v);
    }
  __syncthreads();

  f32x4 acc2[4] = {};
  #pragma unroll
  for (int k = 0; k < 8; ++k) {
    bf16x8 a = *(const bf16x8*)(xr_s + (rh*16 + fr)*264 + k*32 + kg);
    #pragma unroll
    for (int cc = 0; cc < 4; ++cc)
      acc2[cc] = mfma16(a, ldb8(p.Wfr + (size_t)(cq*64 + cc*16 + fr)*256 + k*32 + kg), acc2[cc]);
  }
  float lnum = 0.f;
  #pragma unroll
  for (int cc = 0; cc < 4; ++cc)
    #pragma unroll
    for (int q = 0; q < 4; ++q) {
      const int e = cc*4 + q;
      const int mi = rh*16 + (lane>>4)*4 + q;
      const int n  = cq*64 + cc*16 + fr;
      const float xu  = acc2[cc][q] + p.b_fr[n];
      const float bet = b2f(p.beta[((size_t)t*256 + m0+mi)*256 + n]);
      const float xc  = bet*xu + (1.f-bet)*xhv[e];
      const float xi  = mmv[e]*xxv[e] + (1.f-mmv[e])*xc;
      ximp_s[mi*272 + n] = (u8)f2e4(xi);
      if (cg == 0) {
        const size_t gi = (size_t)(m0+mi)*TF + (size_t)t*256 + n;
        __builtin_nontemporal_store(xc, p.out + OFF_RECON + gi);
        __builtin_nontemporal_store(xi, p.out + gi);
        lnum += fabsf(xc - xxv[e])*mmv[e];
      }
    }
  if (cg == 0) {
    #pragma unroll
    for (int o = 32; o; o >>= 1) lnum += __shfl_down(lnum, o);
    if (lane == 0) atomicAdd(p.num + t, lnum);
  }
  __syncthreads();   // xr_s dead; ximp_s ready

  // ===== B-part: fp8 gates (K=1024), block owns 64 h-cols x 4 gates =====
  const int g = w & 3, rh2 = w >> 2;
  f32x4 ag[4] = {};
  #pragma unroll
  for (int k = 0; k < 8; ++k) {         // K 0..256: x_imp fp8 (LDS)
    const u64 a = *(const u64*)(ximp_s + (size_t)(rh2*16 + fr)*272 + k*32 + kg);
    #pragma unroll
    for (int cc = 0; cc < 4; ++cc)
      ag[cc] = mfma8(a, *(const u64*)(p.Wih8 + (size_t)(g*512 + hc0 + cc*16 + fr)*512 + k*32 + kg), ag[cc]);
  }
  #pragma unroll
  for (int k = 0; k < 8; ++k) {         // K 256..512: mask fp8 (stream)
    const u64 a = __builtin_nontemporal_load(
        (const u64*)(p.mask8 + ((size_t)t*256 + m0 + rh2*16 + fr)*256 + k*32 + kg));
    #pragma unroll
    for (int cc = 0; cc < 4; ++cc)
      ag[cc] = mfma8(a, *(const u64*)(p.Wih8 + (size_t)(g*512 + hc0 + cc*16 + fr)*512 + 256 + k*32 + kg), ag[cc]);
  }
  #pragma unroll
  for (int k = 0; k < 16; ++k) {        // K 512..1024: h_dec fp8 (global, prev step)
    const u64 a = *(const u64*)(h8r + (size_t)(m0 + rh2*16 + fr)*512 + k*32 + kg);
    #pragma unroll
    for (int cc = 0; cc < 4; ++cc)
      ag[cc] = mfma8(a, *(const u64*)(p.Whh8 + (size_t)(g*512 + hc0 + cc*16 + fr)*512 + k*32 + kg), ag[cc]);
  }
  #pragma unroll
  for (int cc = 0; cc < 4; ++cc)
    #pragma unroll
    for (int q = 0; q < 4; ++q) {
      const int row = rh2*16 + (lane>>4)*4 + q;
      const int col = cc*16 + fr;
      pre_s[(g*32 + row)*68 + col] = ag[cc][q];
    }
  __syncthreads();

  // ===== fused LSTM: thread owns (lrow, 4 cols) of block's 32x64 tile =====
  {
    const int lrow = tid >> 4;
    const int lcb  = (tid & 15) * 4;
    float hvv[4], hd[4];
    #pragma unroll
    for (int j = 0; j < 4; ++j) {
      const int n = hc0 + lcb + j;
      const float pi = pre_s[(0*32 + lrow)*68 + lcb + j] + p.b_ih[       n] + p.b_hh[       n];
      const float pf = pre_s[(1*32 + lrow)*68 + lcb + j] + p.b_ih[ 512 + n] + p.b_hh[ 512 + n];
      const float pg = pre_s[(2*32 + lrow)*68 + lcb + j] + p.b_ih[1024 + n] + p.b_hh[1024 + n];
      const float po = pre_s[(3*32 + lrow)*68 + lcb + j] + p.b_ih[1536 + n] + p.b_hh[1536 + n];
      const float ig = sigf(pi), fg = sigf(pf);
      const float gg = tanhf(pg), og = sigf(po);
      const int idx = (m0+lrow)*512 + n;
      const float cv = fg*p.c[idx] + ig*gg;
      p.c[idx] = cv;
      hvv[j] = og*tanhf(cv);
    }
    const int idx0 = (m0+lrow)*512 + hc0 + lcb;
    if (t == Tt-1) {
      #pragma unroll
      for (int j = 0; j < 4; ++j)
        __builtin_nontemporal_store(hvv[j], p.out + OFF_H + idx0 + j);
    } else {
      #pragma unroll
      for (int j = 0; j < 4; ++j) {
        const float gn = b2f(p.gammah[((size_t)(t+1)*256 + m0 + lrow)*512 + hc0 + lcb + j]);
        hd[j] = hvv[j]*gn;
      }
      union { u64 q; u16 h[4]; } pb2;
      pb2.h[0]=f2b(hd[0]); pb2.h[1]=f2b(hd[1]); pb2.h[2]=f2b(hd[2]); pb2.h[3]=f2b(hd[3]);
      *(u64*)(hw + idx0) = pb2.q;
      *(unsigned*)(h8w + idx0) = pk4e4(hd[0], hd[1], hd[2], hd[3]);
    }
  }
}

extern "C" void kernel_launch(void* const* d_in, const int* in_sizes, int n_in,
                              void* d_out, int out_size, void* d_ws, size_t ws_size,
                              hipStream_t stream)
{
  char* wsb = (char*)d_ws;
  float* num   = (float*)(wsb + 0);              //      512
  float* c     = (float*)(wsb + 512);            //   524288
  u16*  hb0    = (u16*)(wsb + 524800);           //   262144
  u8*   h80    = (u8*)(wsb + 786944);            //   131072  (memset through 918016)
  u16*  hb1    = (u16*)(wsb + 918016);           //   262144
  u8*   h81    = (u8*)(wsb + 1180160);           //   131072
  float* den   = (float*)(wsb + 1311232);        //      512
  u8*   mask8  = (u8*)(wsb + 1311744);           //  8388608  [t][b][f]
  u16*  beta   = (u16*)(wsb + 9700352);          // 16777216  [t][b][f]
  u16*  gammah = (u16*)(wsb + 26477568);         // 33554432  [t][b][h]
  u16*  Whist  = (u16*)(wsb + 60032000);         //   262144
  u16*  Wfr    = (u16*)(wsb + 60294144);         //   131072
  u16*  Wgh    = (u16*)(wsb + 60425216);         //   262144
  u16*  Wcomb  = (u16*)(wsb + 60687360);         //   262144
  u8*   Wih8   = (u8*)(wsb + 60949504);          //  1048576
  u8*   Whh8   = (u8*)(wsb + 61998080);          //  1048576  -> 63046656 total

  // zero num, c, hb0, h80 on every (graph-replayed) call (t=0 reads parity-0 buffers)
  hipMemsetAsync(d_ws, 0, 918016, stream);

  k_conv<<<dim3((CV_TOT+255)/256), dim3(256), 0, stream>>>(
      (const float*)d_in[3], (const float*)d_in[7], (const float*)d_in[9],
      (const float*)d_in[11], Wgh, Whist, Wfr, Wcomb);
  k_conv8<<<dim3(4096), dim3(256), 0, stream>>>(
      (const float*)d_in[13], (const float*)d_in[15], Wih8, Whh8);
  k_den<<<dim3(128), dim3(256), 0, stream>>>((const float*)d_in[1], den, mask8);

  P p{};
  p.x = (const float*)d_in[0];  p.mask = (const float*)d_in[1];
  p.deltas = (const float*)d_in[2];
  p.b_gh = (const float*)d_in[4];  p.w_gx = (const float*)d_in[5];
  p.b_gx = (const float*)d_in[6];  p.b_comb = (const float*)d_in[12];
  p.Wgh = Wgh; p.Wcomb = Wcomb;
  p.gammah = gammah; p.beta = beta;
  gk<M_GH><<<dim3(8, 512), dim3(256), 0, stream>>>(p);    // gamma_h, all t
  gk<M_BETA><<<dim3(4, 512), dim3(256), 0, stream>>>(p);  // beta, all t

  PS ps{};
  ps.x = (const float*)d_in[0];  ps.mask = (const float*)d_in[1];
  ps.b_hist = (const float*)d_in[8];  ps.b_fr = (const float*)d_in[10];
  ps.b_ih = (const float*)d_in[14];   ps.b_hh = (const float*)d_in[16];
  ps.Whist = Whist; ps.Wfr = Wfr; ps.gammah = gammah; ps.beta = beta;
  ps.Wih8 = Wih8; ps.Whh8 = Whh8; ps.mask8 = mask8;
  ps.hb0 = hb0; ps.hb1 = hb1; ps.h80 = h80; ps.h81 = h81;
  ps.c = c; ps.num = num; ps.out = (float*)d_out;

  for (int t = 0; t < Tt; ++t)
    k_step<<<dim3(64), dim3(512), 0, stream>>>(ps, t);

  k_final<<<dim3(1), dim3(64), 0, stream>>>(num, den, (float*)d_out);
}

// Round 11
// 5427.340 us; speedup vs baseline: 1.6720x; 1.6720x over previous
//
#include <hip/hip_runtime.h>
#include <hip/hip_bf16.h>

typedef float f32x4 __attribute__((ext_vector_type(4)));
typedef __bf16 bf16x8 __attribute__((ext_vector_type(8)));
typedef short s16x8 __attribute__((ext_vector_type(8)));
typedef unsigned short u16;
typedef unsigned long long u64;
typedef unsigned char u8;

constexpr int Bb = 256, Tt = 128, Ff = 256, Hh = 512;
constexpr int TF = Tt * Ff;                       // 32768
constexpr long OFF_RECON = (long)Bb * Tt * Ff;    // 8388608
constexpr long OFF_H     = 2L * Bb * Tt * Ff;     // 16777216
constexpr long OFF_LOSS  = OFF_H + (long)Bb * Hh; // 16908288

__device__ inline float sigf(float v){ return 1.f / (1.f + expf(-v)); }
__device__ inline u16 f2b(float f){
  unsigned u = __float_as_uint(f);
  u += 0x7fffu + ((u >> 16) & 1u);   // RNE
  return (u16)(u >> 16);
}
__device__ inline float b2f(u16 b){ return __uint_as_float(((unsigned)b) << 16); }

// ---- fp8 e4m3 (OCP) conversion ----
__device__ inline unsigned f2e4_sw(float f){
  unsigned u = __float_as_uint(f);
  unsigned s = (u >> 24) & 0x80u;
  int e = (int)((u >> 23) & 0xff) - 127;
  unsigned m = u & 0x7fffffu;
  if (((u >> 23) & 0xff) == 0xff) return s | 0x7e;
  if (e > 8 || (e == 8 && m > 0x600000)) return s | 0x7e;
  if (e < -10) return s;
  if (e >= -6) {
    unsigned keep = m >> 20, rest = m & 0xfffffu;
    keep += (rest > 0x80000u) || (rest == 0x80000u && (keep & 1));
    unsigned ee = (unsigned)(e + 7);
    if (keep == 8) { keep = 0; ee += 1; }
    if (ee >= 16) return s | 0x7e;
    return s | (ee << 3) | keep;
  }
  unsigned full = (1u << 23) | m;
  int shift = 20 + (-6 - e);
  unsigned keep = full >> shift;
  unsigned rest = full & ((1u << shift) - 1u);
  unsigned half = 1u << (shift - 1);
  keep += (rest > half) || (rest == half && (keep & 1));
  return s | keep;
}
__device__ inline unsigned f2e4(float f){
#if __has_builtin(__builtin_amdgcn_cvt_pk_fp8_f32)
  return (unsigned)__builtin_amdgcn_cvt_pk_fp8_f32(f, f, 0, false) & 0xffu;
#else
  return f2e4_sw(f);
#endif
}
__device__ inline unsigned pk2e4(float a, float b){
#if __has_builtin(__builtin_amdgcn_cvt_pk_fp8_f32)
  return (unsigned)__builtin_amdgcn_cvt_pk_fp8_f32(a, b, 0, false) & 0xffffu;
#else
  return f2e4_sw(a) | (f2e4_sw(b) << 8);
#endif
}

__device__ inline f32x4 mfma16(bf16x8 a, bf16x8 b, f32x4 c){
  return __builtin_amdgcn_mfma_f32_16x16x32_bf16(a, b, c, 0, 0, 0);
}
__device__ inline f32x4 mfma8(u64 a, u64 b, f32x4 c){
  return __builtin_amdgcn_mfma_f32_16x16x32_fp8_fp8((long)a, (long)b, c, 0, 0, 0);
}
__device__ inline bf16x8 ldb8(const u16* p){ return *reinterpret_cast<const bf16x8*>(p); }
__device__ inline bf16x8 cvt8(const float* p){
  const float4 a = ((const float4*)p)[0], b = ((const float4*)p)[1];
  s16x8 r;
  r[0]=f2b(a.x); r[1]=f2b(a.y); r[2]=f2b(a.z); r[3]=f2b(a.w);
  r[4]=f2b(b.x); r[5]=f2b(b.y); r[6]=f2b(b.z); r[7]=f2b(b.w);
  return __builtin_bit_cast(bf16x8, r);
}

// ---------------- hoisted big GEMMs (gamma_h, beta for all t; [t][b] layout) ----------------
enum { M_GH, M_BETA };

struct P {
  const float *x, *mask, *deltas;
  const float *b_gh, *w_gx, *b_gx, *b_comb;
  const u16 *Wgh, *Wcomb;
  u16 *gammah, *beta;
};

template<int MODE>
__global__ __launch_bounds__(256) void gk(P p)
{
  constexpr int K = (MODE==M_GH) ? 256 : 512;
  const int lane = threadIdx.x & 63;
  const int w = threadIdx.x >> 6;
  const int m0 = blockIdx.y*64 + (w>>1)*32;
  const int n0 = blockIdx.x*64 + (w&1)*32;
  const int fr = lane & 15;
  const int kg = (lane >> 4) << 3;

  f32x4 acc[2][2] = {};
  for (int k = 0; k < K; k += 32) {
    const int kk = k + kg;
    bf16x8 a[2], b[2];
    #pragma unroll
    for (int r = 0; r < 2; ++r) {
      const int mr = m0 + 16*r + fr;
      if constexpr (MODE == M_GH) {
        a[r] = cvt8(p.deltas + (size_t)mr*256 + kk);
      } else {
        if (kk < 256) {
          const float4 d0 = *(const float4*)(p.deltas + (size_t)mr*256 + kk);
          const float4 d1 = *(const float4*)(p.deltas + (size_t)mr*256 + kk + 4);
          const float4 w0 = *(const float4*)(p.w_gx + kk);
          const float4 w1 = *(const float4*)(p.w_gx + kk + 4);
          const float4 g0 = *(const float4*)(p.b_gx + kk);
          const float4 g1 = *(const float4*)(p.b_gx + kk + 4);
          s16x8 v;
          v[0]=f2b(expf(-fmaxf(d0.x*w0.x+g0.x,0.f)));
          v[1]=f2b(expf(-fmaxf(d0.y*w0.y+g0.y,0.f)));
          v[2]=f2b(expf(-fmaxf(d0.z*w0.z+g0.z,0.f)));
          v[3]=f2b(expf(-fmaxf(d0.w*w0.w+g0.w,0.f)));
          v[4]=f2b(expf(-fmaxf(d1.x*w1.x+g1.x,0.f)));
          v[5]=f2b(expf(-fmaxf(d1.y*w1.y+g1.y,0.f)));
          v[6]=f2b(expf(-fmaxf(d1.z*w1.z+g1.z,0.f)));
          v[7]=f2b(expf(-fmaxf(d1.w*w1.w+g1.w,0.f)));
          a[r] = __builtin_bit_cast(bf16x8, v);
        } else {
          a[r] = cvt8(p.mask + (size_t)mr*256 + (kk-256));
        }
      }
    }
    #pragma unroll
    for (int cc = 0; cc < 2; ++cc) {
      const int nr = n0 + 16*cc + fr;
      if constexpr (MODE == M_GH) b[cc] = ldb8(p.Wgh   + (size_t)nr*256 + kk);
      else                        b[cc] = ldb8(p.Wcomb + (size_t)nr*512 + kk);
    }
    #pragma unroll
    for (int r = 0; r < 2; ++r)
      #pragma unroll
      for (int cc = 0; cc < 2; ++cc)
        acc[r][cc] = mfma16(a[r], b[cc], acc[r][cc]);
  }

  #pragma unroll
  for (int r = 0; r < 2; ++r)
    #pragma unroll
    for (int cc = 0; cc < 2; ++cc)
      #pragma unroll
      for (int q = 0; q < 4; ++q) {
        const int m = m0 + 16*r + (lane>>4)*4 + q;   // m = b*128 + t
        const int n = n0 + 16*cc + (lane&15);
        const size_t tb = (size_t)(m & 127)*256 + (m >> 7);   // [t][b]
        if constexpr (MODE == M_GH) {
          float v = expf(-fmaxf(acc[r][cc][q] + p.b_gh[n], 0.f));
          p.gammah[tb*512 + n] = f2b(v);
        } else {
          float v = sigf(acc[r][cc][q] + p.b_comb[n]);
          p.beta[tb*256 + n] = f2b(v);
        }
      }
}

// ---------------- weight conversion / den / final ----------------
constexpr int CV_TOT = 131072+131072+65536+131072; // bf16 ones
__global__ __launch_bounds__(256) void k_conv(
    const float* Wgh, const float* Whist, const float* Wfr, const float* Wcomb,
    u16* ogh, u16* ohist, u16* ofr, u16* ocomb)
{
  int i = blockIdx.x*256 + threadIdx.x;
  if (i >= CV_TOT) return;
  int j = i;
  if (j < 131072) { ogh[j] = f2b(Wgh[j]); return; }       j -= 131072;
  if (j < 131072) { ohist[j] = f2b(Whist[j]); return; }   j -= 131072;
  if (j < 65536)  { ofr[j] = ((j>>8)==(j&255)) ? (u16)0 : f2b(Wfr[j]); return; } j -= 65536;
  ocomb[j] = f2b(Wcomb[j]);
}

__global__ __launch_bounds__(256) void k_conv8(
    const float* Wih, const float* Whh, u8* oih, u8* ohh)
{
  int i = blockIdx.x*256 + threadIdx.x;   // pair index, total 1048576
  if (i < 524288) {
    ((u16*)oih)[i] = (u16)pk2e4(Wih[2*i], Wih[2*i+1]);
  } else {
    int j = i - 524288;
    ((u16*)ohh)[j] = (u16)pk2e4(Whh[2*j], Whh[2*j+1]);
  }
}

__global__ __launch_bounds__(256) void k_den(const float* __restrict__ mask,
                                             float* den, u8* mask8)
{
  const int t = blockIdx.x;
  const int f = threadIdx.x;
  float s = 0.f;
  for (int b = 0; b < Bb; ++b) {
    float mv = mask[(size_t)b*TF + (size_t)t*256 + f];
    s += mv;
    mask8[((size_t)t*256 + b)*256 + f] = (u8)f2e4(mv);
  }
  __shared__ float red[4];
  #pragma unroll
  for (int o = 32; o; o >>= 1) s += __shfl_down(s, o);
  if ((f & 63) == 0) red[f >> 6] = s;
  __syncthreads();
  if (f == 0) den[t] = red[0]+red[1]+red[2]+red[3];
}

__global__ void k_final(const float* num, const float* den, float* out)
{
  if (threadIdx.x < 64) {
    int t = threadIdx.x;
    float s = num[t]/(den[t]+1e-12f) + num[t+64]/(den[t+64]+1e-12f);
    #pragma unroll
    for (int o = 32; o; o >>= 1) s += __shfl_down(s, o);
    if (t == 0) { out[OFF_LOSS] = s; out[OFF_LOSS+1] = 0.f; }
  }
}

// ---------------- single per-step kernel: 128 blocks = 16 slabs x 8 col-groups ----------------
struct PS {
  const float *x, *mask;
  const float *b_hist, *b_fr, *b_ih, *b_hh;
  const u16 *Whist, *Wfr, *gammah, *beta;
  const u8 *Wih8, *Whh8, *mask8;
  u16 *hb0, *hb1; u8 *h80, *h81;     // parity double-buffered h (bf16 + fp8)
  float *c, *num, *out;
};

// slab = bid&15 (16 rows); cg = bid>>4 (64 h-cols). All 8 cg-blocks of a slab
// share bid mod 8 -> same XCD (round-robin); per-XCD weights 2.4MB < 4MB L2.
// A-part (XH->xr->XU) computed redundantly by the slab's 8 blocks (LDS-local);
// B-part: block owns 16 rows x 64 h-cols x 4 gates + fused LSTM.
__global__ __launch_bounds__(512) void k_step(PS p, int t)
{
  __shared__ char smem[22016];
  float* pre_s  = (float*)smem;           // [4][16][68] f32 (17408 B; aliases xr_s)
  u16*   xr_s   = (u16*)smem;             // [16][264] bf16 (8448 B)
  u8*    ximp_s = (u8*)(smem + 17408);    // [16][272] fp8 (4352 B)

  const int tid = threadIdx.x, lane = tid & 63, w = tid >> 6;
  const int fr = lane & 15, kg = (lane >> 4) << 3;
  const int slab = blockIdx.x & 15, cg = blockIdx.x >> 4;
  const int m0 = slab*16, hc0 = cg*64;

  const u16* hr = (t & 1) ? p.hb1 : p.hb0;
  u16*       hw = (t & 1) ? p.hb0 : p.hb1;
  const u8*  h8r = (t & 1) ? p.h81 : p.h80;
  u8*        h8w = (t & 1) ? p.h80 : p.h81;

  // ===== A-part: XH (K=512) -> xr(LDS) -> XU (K=256); wave owns 32 n-cols =====
  const int nA0 = w * 32;
  f32x4 acc[2] = {};
  #pragma unroll
  for (int k = 0; k < 16; ++k) {
    bf16x8 a = ldb8(hr + (size_t)(m0 + fr)*512 + k*32 + kg);
    #pragma unroll
    for (int cc = 0; cc < 2; ++cc)
      acc[cc] = mfma16(a, ldb8(p.Whist + (size_t)(nA0 + cc*16 + fr)*512 + k*32 + kg), acc[cc]);
  }
  float xhv[8];
  #pragma unroll
  for (int cc = 0; cc < 2; ++cc)
    #pragma unroll
    for (int q = 0; q < 4; ++q) {
      const int row = (lane>>4)*4 + q;          // 0..15
      const int n   = nA0 + cc*16 + fr;
      const float v = acc[cc][q] + p.b_hist[n];
      xhv[cc*4+q] = v;
      const size_t gi = (size_t)(m0+row)*TF + (size_t)t*256 + n;
      const float mm = p.mask[gi];
      const float xx = p.x[gi];
      xr_s[row*264 + n] = f2b(mm*xx + (1.f-mm)*v);
    }
  __syncthreads();

  f32x4 acc2[2] = {};
  #pragma unroll
  for (int k = 0; k < 8; ++k) {
    bf16x8 a = *(const bf16x8*)(xr_s + fr*264 + k*32 + kg);
    #pragma unroll
    for (int cc = 0; cc < 2; ++cc)
      acc2[cc] = mfma16(a, ldb8(p.Wfr + (size_t)(nA0 + cc*16 + fr)*256 + k*32 + kg), acc2[cc]);
  }
  float lnum = 0.f;
  #pragma unroll
  for (int cc = 0; cc < 2; ++cc)
    #pragma unroll
    for (int q = 0; q < 4; ++q) {
      const int row = (lane>>4)*4 + q;
      const int n   = nA0 + cc*16 + fr;
      const float xu  = acc2[cc][q] + p.b_fr[n];
      const float bet = b2f(p.beta[((size_t)t*256 + m0+row)*256 + n]);
      const float xc  = bet*xu + (1.f-bet)*xhv[cc*4+q];
      const size_t gi = (size_t)(m0+row)*TF + (size_t)t*256 + n;
      const float mm = p.mask[gi];            // L1 hit (loaded above)
      const float xx = p.x[gi];
      const float xi = mm*xx + (1.f-mm)*xc;
      ximp_s[row*272 + n] = (u8)f2e4(xi);
      if (cg == 0) {
        __builtin_nontemporal_store(xc, p.out + OFF_RECON + gi);
        __builtin_nontemporal_store(xi, p.out + gi);
        lnum += fabsf(xc - xx)*mm;
      }
    }
  if (cg == 0) {
    #pragma unroll
    for (int o = 32; o; o >>= 1) lnum += __shfl_down(lnum, o);
    if (lane == 0) atomicAdd(p.num + t, lnum);
  }
  __syncthreads();   // xr_s dead; ximp_s ready

  // ===== B-part: fp8 gates (K=1024); wave = (gate g, col-half) -> 32 cols =====
  const int g = w >> 1, half = w & 1;
  f32x4 ag[2] = {};
  #pragma unroll
  for (int k = 0; k < 8; ++k) {         // K 0..256: x_imp fp8 (LDS)
    const u64 a = *(const u64*)(ximp_s + (size_t)fr*272 + k*32 + kg);
    #pragma unroll
    for (int cc = 0; cc < 2; ++cc)
      ag[cc] = mfma8(a, *(const u64*)(p.Wih8 + (size_t)(g*512 + hc0 + half*32 + cc*16 + fr)*512 + k*32 + kg), ag[cc]);
  }
  #pragma unroll
  for (int k = 0; k < 8; ++k) {         // K 256..512: mask fp8
    const u64 a = *(const u64*)(p.mask8 + ((size_t)t*256 + m0 + fr)*256 + k*32 + kg);
    #pragma unroll
    for (int cc = 0; cc < 2; ++cc)
      ag[cc] = mfma8(a, *(const u64*)(p.Wih8 + (size_t)(g*512 + hc0 + half*32 + cc*16 + fr)*512 + 256 + k*32 + kg), ag[cc]);
  }
  #pragma unroll
  for (int k = 0; k < 16; ++k) {        // K 512..1024: h_dec fp8 (prev step)
    const u64 a = *(const u64*)(h8r + (size_t)(m0 + fr)*512 + k*32 + kg);
    #pragma unroll
    for (int cc = 0; cc < 2; ++cc)
      ag[cc] = mfma8(a, *(const u64*)(p.Whh8 + (size_t)(g*512 + hc0 + half*32 + cc*16 + fr)*512 + k*32 + kg), ag[cc]);
  }
  #pragma unroll
  for (int cc = 0; cc < 2; ++cc)
    #pragma unroll
    for (int q = 0; q < 4; ++q) {
      const int row = (lane>>4)*4 + q;
      const int col = half*32 + cc*16 + fr;
      pre_s[(g*16 + row)*68 + col] = ag[cc][q];
    }
  __syncthreads();

  // ===== fused LSTM: thread owns (lrow, 2 cols) of block's 16x64 tile =====
  {
    const int lrow  = tid >> 5;            // 0..15
    const int lcolp = (tid & 31) * 2;      // 0,2,..,62
    float hd[2]; float hvv[2];
    #pragma unroll
    for (int j = 0; j < 2; ++j) {
      const int lcol = lcolp + j;
      const int n = hc0 + lcol;
      const float pi = pre_s[(0*16 + lrow)*68 + lcol] + p.b_ih[       n] + p.b_hh[       n];
      const float pf = pre_s[(1*16 + lrow)*68 + lcol] + p.b_ih[ 512 + n] + p.b_hh[ 512 + n];
      const float pg = pre_s[(2*16 + lrow)*68 + lcol] + p.b_ih[1024 + n] + p.b_hh[1024 + n];
      const float po = pre_s[(3*16 + lrow)*68 + lcol] + p.b_ih[1536 + n] + p.b_hh[1536 + n];
      const float ig = sigf(pi), fg = sigf(pf);
      const float gg = tanhf(pg), og = sigf(po);
      const int idx = (m0+lrow)*512 + n;
      const float cv = fg*p.c[idx] + ig*gg;
      p.c[idx] = cv;
      hvv[j] = og*tanhf(cv);
    }
    const int idx0 = (m0+lrow)*512 + hc0 + lcolp;
    if (t == Tt-1) {
      __builtin_nontemporal_store(hvv[0], p.out + OFF_H + idx0);
      __builtin_nontemporal_store(hvv[1], p.out + OFF_H + idx0 + 1);
    } else {
      #pragma unroll
      for (int j = 0; j < 2; ++j) {
        const float gn = b2f(__builtin_nontemporal_load(
            p.gammah + ((size_t)(t+1)*256 + m0 + lrow)*512 + hc0 + lcolp + j));
        hd[j] = hvv[j]*gn;
      }
      union { unsigned u; u16 h[2]; } pb2;
      pb2.h[0] = f2b(hd[0]); pb2.h[1] = f2b(hd[1]);
      *(unsigned*)(hw + idx0) = pb2.u;
      *(u16*)(h8w + idx0) = (u16)pk2e4(hd[0], hd[1]);
    }
  }
}

extern "C" void kernel_launch(void* const* d_in, const int* in_sizes, int n_in,
                              void* d_out, int out_size, void* d_ws, size_t ws_size,
                              hipStream_t stream)
{
  char* wsb = (char*)d_ws;
  float* num   = (float*)(wsb + 0);              //      512
  float* c     = (float*)(wsb + 512);            //   524288
  u16*  hb0    = (u16*)(wsb + 524800);           //   262144
  u8*   h80    = (u8*)(wsb + 786944);            //   131072  (memset through 918016)
  u16*  hb1    = (u16*)(wsb + 918016);           //   262144
  u8*   h81    = (u8*)(wsb + 1180160);           //   131072
  float* den   = (float*)(wsb + 1311232);        //      512
  u8*   mask8  = (u8*)(wsb + 1311744);           //  8388608  [t][b][f]
  u16*  beta   = (u16*)(wsb + 9700352);          // 16777216  [t][b][f]
  u16*  gammah = (u16*)(wsb + 26477568);         // 33554432  [t][b][h]
  u16*  Whist  = (u16*)(wsb + 60032000);         //   262144
  u16*  Wfr    = (u16*)(wsb + 60294144);         //   131072
  u16*  Wgh    = (u16*)(wsb + 60425216);         //   262144
  u16*  Wcomb  = (u16*)(wsb + 60687360);         //   262144
  u8*   Wih8   = (u8*)(wsb + 60949504);          //  1048576
  u8*   Whh8   = (u8*)(wsb + 61998080);          //  1048576  -> 63046656 total

  // zero num, c, hb0, h80 on every (graph-replayed) call (t=0 reads parity-0 buffers)
  hipMemsetAsync(d_ws, 0, 918016, stream);

  k_conv<<<dim3((CV_TOT+255)/256), dim3(256), 0, stream>>>(
      (const float*)d_in[3], (const float*)d_in[7], (const float*)d_in[9],
      (const float*)d_in[11], Wgh, Whist, Wfr, Wcomb);
  k_conv8<<<dim3(4096), dim3(256), 0, stream>>>(
      (const float*)d_in[13], (const float*)d_in[15], Wih8, Whh8);
  k_den<<<dim3(128), dim3(256), 0, stream>>>((const float*)d_in[1], den, mask8);

  P p{};
  p.x = (const float*)d_in[0];  p.mask = (const float*)d_in[1];
  p.deltas = (const float*)d_in[2];
  p.b_gh = (const float*)d_in[4];  p.w_gx = (const float*)d_in[5];
  p.b_gx = (const float*)d_in[6];  p.b_comb = (const float*)d_in[12];
  p.Wgh = Wgh; p.Wcomb = Wcomb;
  p.gammah = gammah; p.beta = beta;
  gk<M_GH><<<dim3(8, 512), dim3(256), 0, stream>>>(p);    // gamma_h, all t
  gk<M_BETA><<<dim3(4, 512), dim3(256), 0, stream>>>(p);  // beta, all t

  PS ps{};
  ps.x = (const float*)d_in[0];  ps.mask = (const float*)d_in[1];
  ps.b_hist = (const float*)d_in[8];  ps.b_fr = (const float*)d_in[10];
  ps.b_ih = (const float*)d_in[14];   ps.b_hh = (const float*)d_in[16];
  ps.Whist = Whist; ps.Wfr = Wfr; ps.gammah = gammah; ps.beta = beta;
  ps.Wih8 = Wih8; ps.Whh8 = Whh8; ps.mask8 = mask8;
  ps.hb0 = hb0; ps.hb1 = hb1; ps.h80 = h80; ps.h81 = h81;
  ps.c = c; ps.num = num; ps.out = (float*)d_out;

  for (int t = 0; t < Tt; ++t)
    k_step<<<dim3(128), dim3(512), 0, stream>>>(ps, t);

  k_final<<<dim3(1), dim3(64), 0, stream>>>(num, den, (float*)d_out);
}

// Round 12
// 5047.260 us; speedup vs baseline: 1.7979x; 1.0753x over previous
//
#include <hip/hip_runtime.h>
#include <hip/hip_bf16.h>

typedef float f32x4 __attribute__((ext_vector_type(4)));
typedef __bf16 bf16x8 __attribute__((ext_vector_type(8)));
typedef short s16x8 __attribute__((ext_vector_type(8)));
typedef unsigned short u16;
typedef unsigned long long u64;
typedef unsigned char u8;

constexpr int Bb = 256, Tt = 128, Ff = 256, Hh = 512;
constexpr int TF = Tt * Ff;                       // 32768
constexpr long OFF_RECON = (long)Bb * Tt * Ff;    // 8388608
constexpr long OFF_H     = 2L * Bb * Tt * Ff;     // 16777216
constexpr long OFF_LOSS  = OFF_H + (long)Bb * Hh; // 16908288

__device__ inline float sigf(float v){ return 1.f / (1.f + expf(-v)); }
__device__ inline u16 f2b(float f){
  unsigned u = __float_as_uint(f);
  u += 0x7fffu + ((u >> 16) & 1u);   // RNE
  return (u16)(u >> 16);
}
__device__ inline float b2f(u16 b){ return __uint_as_float(((unsigned)b) << 16); }

// ---- fp8 e4m3 (OCP) conversion ----
__device__ inline unsigned f2e4_sw(float f){
  unsigned u = __float_as_uint(f);
  unsigned s = (u >> 24) & 0x80u;
  int e = (int)((u >> 23) & 0xff) - 127;
  unsigned m = u & 0x7fffffu;
  if (((u >> 23) & 0xff) == 0xff) return s | 0x7e;
  if (e > 8 || (e == 8 && m > 0x600000)) return s | 0x7e;
  if (e < -10) return s;
  if (e >= -6) {
    unsigned keep = m >> 20, rest = m & 0xfffffu;
    keep += (rest > 0x80000u) || (rest == 0x80000u && (keep & 1));
    unsigned ee = (unsigned)(e + 7);
    if (keep == 8) { keep = 0; ee += 1; }
    if (ee >= 16) return s | 0x7e;
    return s | (ee << 3) | keep;
  }
  unsigned full = (1u << 23) | m;
  int shift = 20 + (-6 - e);
  unsigned keep = full >> shift;
  unsigned rest = full & ((1u << shift) - 1u);
  unsigned half = 1u << (shift - 1);
  keep += (rest > half) || (rest == half && (keep & 1));
  return s | keep;
}
__device__ inline unsigned f2e4(float f){
#if __has_builtin(__builtin_amdgcn_cvt_pk_fp8_f32)
  return (unsigned)__builtin_amdgcn_cvt_pk_fp8_f32(f, f, 0, false) & 0xffu;
#else
  return f2e4_sw(f);
#endif
}
__device__ inline unsigned pk2e4(float a, float b){
#if __has_builtin(__builtin_amdgcn_cvt_pk_fp8_f32)
  return (unsigned)__builtin_amdgcn_cvt_pk_fp8_f32(a, b, 0, false) & 0xffffu;
#else
  return f2e4_sw(a) | (f2e4_sw(b) << 8);
#endif
}

__device__ inline f32x4 mfma16(bf16x8 a, bf16x8 b, f32x4 c){
  return __builtin_amdgcn_mfma_f32_16x16x32_bf16(a, b, c, 0, 0, 0);
}
__device__ inline f32x4 mfma8(u64 a, u64 b, f32x4 c){
  return __builtin_amdgcn_mfma_f32_16x16x32_fp8_fp8((long)a, (long)b, c, 0, 0, 0);
}
__device__ inline bf16x8 ldb8(const u16* p){ return *reinterpret_cast<const bf16x8*>(p); }
__device__ inline bf16x8 cvt8(const float* p){
  const float4 a = ((const float4*)p)[0], b = ((const float4*)p)[1];
  s16x8 r;
  r[0]=f2b(a.x); r[1]=f2b(a.y); r[2]=f2b(a.z); r[3]=f2b(a.w);
  r[4]=f2b(b.x); r[5]=f2b(b.y); r[6]=f2b(b.z); r[7]=f2b(b.w);
  return __builtin_bit_cast(bf16x8, r);
}

// ---------------- hoisted big GEMMs (gamma_h, beta for all t; [t][b] layout) ----------------
enum { M_GH, M_BETA };

struct P {
  const float *x, *mask, *deltas;
  const float *b_gh, *w_gx, *b_gx, *b_comb;
  const u16 *Wgh, *Wcomb;
  u16 *gammah, *beta;
};

template<int MODE>
__global__ __launch_bounds__(256) void gk(P p)
{
  constexpr int K = (MODE==M_GH) ? 256 : 512;
  const int lane = threadIdx.x & 63;
  const int w = threadIdx.x >> 6;
  const int m0 = blockIdx.y*64 + (w>>1)*32;
  const int n0 = blockIdx.x*64 + (w&1)*32;
  const int fr = lane & 15;
  const int kg = (lane >> 4) << 3;

  f32x4 acc[2][2] = {};
  for (int k = 0; k < K; k += 32) {
    const int kk = k + kg;
    bf16x8 a[2], b[2];
    #pragma unroll
    for (int r = 0; r < 2; ++r) {
      const int mr = m0 + 16*r + fr;
      if constexpr (MODE == M_GH) {
        a[r] = cvt8(p.deltas + (size_t)mr*256 + kk);
      } else {
        if (kk < 256) {
          const float4 d0 = *(const float4*)(p.deltas + (size_t)mr*256 + kk);
          const float4 d1 = *(const float4*)(p.deltas + (size_t)mr*256 + kk + 4);
          const float4 w0 = *(const float4*)(p.w_gx + kk);
          const float4 w1 = *(const float4*)(p.w_gx + kk + 4);
          const float4 g0 = *(const float4*)(p.b_gx + kk);
          const float4 g1 = *(const float4*)(p.b_gx + kk + 4);
          s16x8 v;
          v[0]=f2b(expf(-fmaxf(d0.x*w0.x+g0.x,0.f)));
          v[1]=f2b(expf(-fmaxf(d0.y*w0.y+g0.y,0.f)));
          v[2]=f2b(expf(-fmaxf(d0.z*w0.z+g0.z,0.f)));
          v[3]=f2b(expf(-fmaxf(d0.w*w0.w+g0.w,0.f)));
          v[4]=f2b(expf(-fmaxf(d1.x*w1.x+g1.x,0.f)));
          v[5]=f2b(expf(-fmaxf(d1.y*w1.y+g1.y,0.f)));
          v[6]=f2b(expf(-fmaxf(d1.z*w1.z+g1.z,0.f)));
          v[7]=f2b(expf(-fmaxf(d1.w*w1.w+g1.w,0.f)));
          a[r] = __builtin_bit_cast(bf16x8, v);
        } else {
          a[r] = cvt8(p.mask + (size_t)mr*256 + (kk-256));
        }
      }
    }
    #pragma unroll
    for (int cc = 0; cc < 2; ++cc) {
      const int nr = n0 + 16*cc + fr;
      if constexpr (MODE == M_GH) b[cc] = ldb8(p.Wgh   + (size_t)nr*256 + kk);
      else                        b[cc] = ldb8(p.Wcomb + (size_t)nr*512 + kk);
    }
    #pragma unroll
    for (int r = 0; r < 2; ++r)
      #pragma unroll
      for (int cc = 0; cc < 2; ++cc)
        acc[r][cc] = mfma16(a[r], b[cc], acc[r][cc]);
  }

  #pragma unroll
  for (int r = 0; r < 2; ++r)
    #pragma unroll
    for (int cc = 0; cc < 2; ++cc)
      #pragma unroll
      for (int q = 0; q < 4; ++q) {
        const int m = m0 + 16*r + (lane>>4)*4 + q;   // m = b*128 + t
        const int n = n0 + 16*cc + (lane&15);
        const size_t tb = (size_t)(m & 127)*256 + (m >> 7);   // [t][b]
        if constexpr (MODE == M_GH) {
          float v = expf(-fmaxf(acc[r][cc][q] + p.b_gh[n], 0.f));
          p.gammah[tb*512 + n] = f2b(v);
        } else {
          float v = sigf(acc[r][cc][q] + p.b_comb[n]);
          p.beta[tb*256 + n] = f2b(v);
        }
      }
}

// ---------------- weight conversion / den / final ----------------
constexpr int CV_TOT = 131072+131072+65536+131072; // bf16 ones
__global__ __launch_bounds__(256) void k_conv(
    const float* Wgh, const float* Whist, const float* Wfr, const float* Wcomb,
    u16* ogh, u16* ohist, u16* ofr, u16* ocomb)
{
  int i = blockIdx.x*256 + threadIdx.x;
  if (i >= CV_TOT) return;
  int j = i;
  if (j < 131072) { ogh[j] = f2b(Wgh[j]); return; }       j -= 131072;
  if (j < 131072) { ohist[j] = f2b(Whist[j]); return; }   j -= 131072;
  if (j < 65536)  { ofr[j] = ((j>>8)==(j&255)) ? (u16)0 : f2b(Wfr[j]); return; } j -= 65536;
  ocomb[j] = f2b(Wcomb[j]);
}

__global__ __launch_bounds__(256) void k_conv8(
    const float* Wih, const float* Whh, u8* oih, u8* ohh)
{
  int i = blockIdx.x*256 + threadIdx.x;   // pair index, total 1048576
  if (i < 524288) {
    ((u16*)oih)[i] = (u16)pk2e4(Wih[2*i], Wih[2*i+1]);
  } else {
    int j = i - 524288;
    ((u16*)ohh)[j] = (u16)pk2e4(Whh[2*j], Whh[2*j+1]);
  }
}

__global__ __launch_bounds__(256) void k_den(const float* __restrict__ mask,
                                             float* den, u8* mask8)
{
  const int t = blockIdx.x;
  const int f = threadIdx.x;
  float s = 0.f;
  for (int b = 0; b < Bb; ++b) {
    float mv = mask[(size_t)b*TF + (size_t)t*256 + f];
    s += mv;
    mask8[((size_t)t*256 + b)*256 + f] = (u8)f2e4(mv);
  }
  __shared__ float red[4];
  #pragma unroll
  for (int o = 32; o; o >>= 1) s += __shfl_down(s, o);
  if ((f & 63) == 0) red[f >> 6] = s;
  __syncthreads();
  if (f == 0) den[t] = red[0]+red[1]+red[2]+red[3];
}

__global__ void k_final(const float* num, const float* den, float* out)
{
  if (threadIdx.x < 64) {
    int t = threadIdx.x;
    float s = num[t]/(den[t]+1e-12f) + num[t+64]/(den[t+64]+1e-12f);
    #pragma unroll
    for (int o = 32; o; o >>= 1) s += __shfl_down(s, o);
    if (t == 0) { out[OFF_LOSS] = s; out[OFF_LOSS+1] = 0.f; }
  }
}

// ---------------- persistent recurrence: 16 slabs x 8 cg-blocks, relaxed flag sync ----------------
struct PSP {
  const float *x, *mask;
  const float *b_hist, *b_fr, *b_ih, *b_hh;
  const u16 *Whist, *Wfr, *gammah, *beta;
  const u8 *Wih8, *Whh8, *mask8;
  u16 *hb0, *hb1; u8 *h80, *h81;     // parity double-buffered h (bf16 + fp8)
  float *num, *out;
  unsigned *flags; int *xcc;
};

// slab = bid&15 (16 rows); cg = bid>>4 (64 h-cols). Slab members bid = slab+16j
// all ≡ slab (mod 8) -> same XCD (verified at runtime). Handoff: plain h stores
// (write-through L1 -> local L2) + vmcnt(0) + RELAXED flag; consumers poll
// RELAXED and read h via sc0 (L1-bypass) from the shared L2. NO acquire/release
// on the fast path -> no L2 invalidate/writeback -> weights stay resident.
__global__ __launch_bounds__(512, 1) void k_loopP(PSP p)
{
  __shared__ char smem[22016];
  float* pre_s  = (float*)smem;           // [4][16][68] f32 (17408 B; aliases xr_s)
  u16*   xr_s   = (u16*)smem;             // [16][264] bf16 (8448 B)
  u8*    ximp_s = (u8*)(smem + 17408);    // [16][272] fp8 (4352 B)
  __shared__ int s_fast;

  const int tid = threadIdx.x, lane = tid & 63, w = tid >> 6;
  const int fr = lane & 15, kg = (lane >> 4) << 3;
  const int bid = blockIdx.x;
  const int slab = bid & 15, cg = bid >> 4;
  const int m0 = slab*16, hc0 = cg*64;

  // publish XCC id; decide fast (same-XCD slab) path
  if (tid == 0) {
    unsigned xv;
    asm volatile("s_getreg_b32 %0, hwreg(HW_REG_XCC_ID)" : "=s"(xv));
    __hip_atomic_store(p.xcc + bid, (int)(xv & 15u) + 1, __ATOMIC_RELAXED, __HIP_MEMORY_SCOPE_AGENT);
    int v0 = 0, ok = 1;
    #pragma unroll 1
    for (int j = 0; j < 8; ++j) {
      int v; unsigned spin = 0;
      do {
        v = __hip_atomic_load(p.xcc + slab + 16*j, __ATOMIC_RELAXED, __HIP_MEMORY_SCOPE_AGENT);
        if (v) break;
        __builtin_amdgcn_s_sleep(8);
      } while (++spin < (1u<<22));
      if (j == 0) v0 = v;
      ok &= (v != 0) && (v == v0);
    }
    s_fast = ok;
  }
  __syncthreads();
  const int fast = s_fast;

  // hoisted per-lane biases
  const int nA0 = w * 32;
  float bh[2], bf2[2];
  #pragma unroll
  for (int cc = 0; cc < 2; ++cc) {
    bh[cc]  = p.b_hist[nA0 + cc*16 + fr];
    bf2[cc] = p.b_fr  [nA0 + cc*16 + fr];
  }
  const int gB = w >> 1, half = w & 1;        // B-part wave roles
  const int lrow = tid >> 5, lcolp = (tid & 31) * 2;
  float bsum[4][2];
  #pragma unroll
  for (int g = 0; g < 4; ++g)
    #pragma unroll
    for (int j = 0; j < 2; ++j) {
      const int n = hc0 + lcolp + j;
      bsum[g][j] = p.b_ih[g*512 + n] + p.b_hh[g*512 + n];
    }
  float c0 = 0.f, c1 = 0.f;

  for (int t = 0; t < Tt; ++t) {
    const u16* hr  = (t & 1) ? p.hb1 : p.hb0;
    u16*       hw  = (t & 1) ? p.hb0 : p.hb1;
    const u8*  h8r = (t & 1) ? p.h81 : p.h80;
    u8*        h8w = (t & 1) ? p.h80 : p.h81;

    // ===== wait for all slab members to finish step t-1 =====
    if (t > 0) {
      if (w == 0 && lane < 8) {
        const unsigned tgt = (unsigned)t;
        unsigned* mf = p.flags + (size_t)(slab + 16*lane)*16;
        unsigned spin = 0;
        if (fast) {
          while (__hip_atomic_load(mf, __ATOMIC_RELAXED, __HIP_MEMORY_SCOPE_AGENT) < tgt
                 && spin < (1u<<24)) { __builtin_amdgcn_s_sleep(1); ++spin; }
        } else {
          while (__hip_atomic_load(mf, __ATOMIC_ACQUIRE, __HIP_MEMORY_SCOPE_AGENT) < tgt
                 && spin < (1u<<24)) { __builtin_amdgcn_s_sleep(1); ++spin; }
        }
      }
      __syncthreads();
      __builtin_amdgcn_sched_barrier(0);
    }

    // ===== A-part: XH (K=512, h via sc0) -> xr(LDS) -> XU (K=256) =====
    bf16x8 ah[16];
    {
      const u16* hb = hr + (size_t)(m0 + fr)*512 + kg;
      #pragma unroll
      for (int i = 0; i < 16; ++i) {
        const u16* pa = hb + i*32;
        asm volatile("global_load_dwordx4 %0, %1, off sc0" : "=&v"(ah[i]) : "v"(pa));
      }
      asm volatile("s_waitcnt vmcnt(0)" ::: "memory");
      __builtin_amdgcn_sched_barrier(0);
    }
    f32x4 acc[2] = {};
    #pragma unroll
    for (int k = 0; k < 16; ++k) {
      #pragma unroll
      for (int cc = 0; cc < 2; ++cc)
        acc[cc] = mfma16(ah[k], ldb8(p.Whist + (size_t)(nA0 + cc*16 + fr)*512 + k*32 + kg), acc[cc]);
    }
    float xhv[8];
    #pragma unroll
    for (int cc = 0; cc < 2; ++cc)
      #pragma unroll
      for (int q = 0; q < 4; ++q) {
        const int row = (lane>>4)*4 + q;          // 0..15
        const int n   = nA0 + cc*16 + fr;
        const float v = acc[cc][q] + bh[cc];
        xhv[cc*4+q] = v;
        const size_t gi = (size_t)(m0+row)*TF + (size_t)t*256 + n;
        const float mm = p.mask[gi];
        const float xx = p.x[gi];
        xr_s[row*264 + n] = f2b(mm*xx + (1.f-mm)*v);
      }
    __syncthreads();

    f32x4 acc2[2] = {};
    #pragma unroll
    for (int k = 0; k < 8; ++k) {
      bf16x8 a = *(const bf16x8*)(xr_s + fr*264 + k*32 + kg);
      #pragma unroll
      for (int cc = 0; cc < 2; ++cc)
        acc2[cc] = mfma16(a, ldb8(p.Wfr + (size_t)(nA0 + cc*16 + fr)*256 + k*32 + kg), acc2[cc]);
    }
    float lnum = 0.f;
    #pragma unroll
    for (int cc = 0; cc < 2; ++cc)
      #pragma unroll
      for (int q = 0; q < 4; ++q) {
        const int row = (lane>>4)*4 + q;
        const int n   = nA0 + cc*16 + fr;
        const float xu  = acc2[cc][q] + bf2[cc];
        const float bet = b2f(p.beta[((size_t)t*256 + m0+row)*256 + n]);
        const float xc  = bet*xu + (1.f-bet)*xhv[cc*4+q];
        const size_t gi = (size_t)(m0+row)*TF + (size_t)t*256 + n;
        const float mm = p.mask[gi];            // L1 hit
        const float xx = p.x[gi];
        const float xi = mm*xx + (1.f-mm)*xc;
        ximp_s[row*272 + n] = (u8)f2e4(xi);
        if (cg == 0) {
          __builtin_nontemporal_store(xc, p.out + OFF_RECON + gi);
          __builtin_nontemporal_store(xi, p.out + gi);
          lnum += fabsf(xc - xx)*mm;
        }
      }
    if (cg == 0) {
      #pragma unroll
      for (int o = 32; o; o >>= 1) lnum += __shfl_down(lnum, o);
      if (lane == 0) atomicAdd(p.num + t, lnum);
    }
    __syncthreads();   // xr_s dead; ximp_s ready

    // ===== B-part: fp8 gates (K=1024); wave = (gate, col-half) =====
    u64 a8[16];
    {
      const u8* h8b = h8r + (size_t)(m0 + fr)*512 + kg;
      #pragma unroll
      for (int i = 0; i < 16; ++i) {
        const u8* pa = h8b + i*32;
        asm volatile("global_load_dwordx2 %0, %1, off sc0" : "=&v"(a8[i]) : "v"(pa));
      }
    }
    f32x4 ag[2] = {};
    #pragma unroll
    for (int k = 0; k < 8; ++k) {         // K 0..256: x_imp fp8 (LDS)
      const u64 a = *(const u64*)(ximp_s + (size_t)fr*272 + k*32 + kg);
      #pragma unroll
      for (int cc = 0; cc < 2; ++cc)
        ag[cc] = mfma8(a, *(const u64*)(p.Wih8 + (size_t)(gB*512 + hc0 + half*32 + cc*16 + fr)*512 + k*32 + kg), ag[cc]);
    }
    #pragma unroll
    for (int k = 0; k < 8; ++k) {         // K 256..512: mask fp8
      const u64 a = *(const u64*)(p.mask8 + ((size_t)t*256 + m0 + fr)*256 + k*32 + kg);
      #pragma unroll
      for (int cc = 0; cc < 2; ++cc)
        ag[cc] = mfma8(a, *(const u64*)(p.Wih8 + (size_t)(gB*512 + hc0 + half*32 + cc*16 + fr)*512 + 256 + k*32 + kg), ag[cc]);
    }
    asm volatile("s_waitcnt vmcnt(0)" ::: "memory");
    __builtin_amdgcn_sched_barrier(0);
    #pragma unroll
    for (int k = 0; k < 16; ++k) {        // K 512..1024: h_dec fp8 (registers)
      #pragma unroll
      for (int cc = 0; cc < 2; ++cc)
        ag[cc] = mfma8(a8[k], *(const u64*)(p.Whh8 + (size_t)(gB*512 + hc0 + half*32 + cc*16 + fr)*512 + k*32 + kg), ag[cc]);
    }
    #pragma unroll
    for (int cc = 0; cc < 2; ++cc)
      #pragma unroll
      for (int q = 0; q < 4; ++q) {
        const int row = (lane>>4)*4 + q;
        const int col = half*32 + cc*16 + fr;
        pre_s[(gB*16 + row)*68 + col] = ag[cc][q];
      }
    __syncthreads();

    // ===== fused LSTM: thread owns (lrow, 2 cols); c in registers =====
    {
      float hvv[2];
      {
        const float pi = pre_s[(0*16 + lrow)*68 + lcolp] + bsum[0][0];
        const float pf = pre_s[(1*16 + lrow)*68 + lcolp] + bsum[1][0];
        const float pg = pre_s[(2*16 + lrow)*68 + lcolp] + bsum[2][0];
        const float po = pre_s[(3*16 + lrow)*68 + lcolp] + bsum[3][0];
        const float cv = sigf(pf)*c0 + sigf(pi)*tanhf(pg);
        c0 = cv; hvv[0] = sigf(po)*tanhf(cv);
      }
      {
        const float pi = pre_s[(0*16 + lrow)*68 + lcolp+1] + bsum[0][1];
        const float pf = pre_s[(1*16 + lrow)*68 + lcolp+1] + bsum[1][1];
        const float pg = pre_s[(2*16 + lrow)*68 + lcolp+1] + bsum[2][1];
        const float po = pre_s[(3*16 + lrow)*68 + lcolp+1] + bsum[3][1];
        const float cv = sigf(pf)*c1 + sigf(pi)*tanhf(pg);
        c1 = cv; hvv[1] = sigf(po)*tanhf(cv);
      }
      const int idx0 = (m0+lrow)*512 + hc0 + lcolp;
      if (t == Tt-1) {
        __builtin_nontemporal_store(hvv[0], p.out + OFF_H + idx0);
        __builtin_nontemporal_store(hvv[1], p.out + OFF_H + idx0 + 1);
      } else {
        float hd[2];
        #pragma unroll
        for (int j = 0; j < 2; ++j) {
          const float gn = b2f(__builtin_nontemporal_load(
              p.gammah + ((size_t)(t+1)*256 + m0 + lrow)*512 + hc0 + lcolp + j));
          hd[j] = hvv[j]*gn;
        }
        union { unsigned u; u16 h[2]; } pb2;
        pb2.h[0] = f2b(hd[0]); pb2.h[1] = f2b(hd[1]);
        *(unsigned*)(hw + idx0) = pb2.u;            // plain: write-through to L2
        *(u16*)(h8w + idx0) = (u16)pk2e4(hd[0], hd[1]);
      }
    }

    // ===== publish step completion =====
    if (t < Tt-1) {
      asm volatile("s_waitcnt vmcnt(0)" ::: "memory");
      __syncthreads();
      if (tid == 0) {
        if (fast)
          __hip_atomic_store(p.flags + (size_t)bid*16, (unsigned)(t+1),
                             __ATOMIC_RELAXED, __HIP_MEMORY_SCOPE_AGENT);
        else
          __hip_atomic_store(p.flags + (size_t)bid*16, (unsigned)(t+1),
                             __ATOMIC_RELEASE, __HIP_MEMORY_SCOPE_AGENT);
      }
    }
  }
}

extern "C" void kernel_launch(void* const* d_in, const int* in_sizes, int n_in,
                              void* d_out, int out_size, void* d_ws, size_t ws_size,
                              hipStream_t stream)
{
  char* wsb = (char*)d_ws;
  unsigned* flags = (unsigned*)(wsb + 0);        //     8192 (128 x 64B)
  int*      xcc   = (int*)(wsb + 8192);          //      512
  float*    num   = (float*)(wsb + 8704);        //      512
  u16*  hb0    = (u16*)(wsb + 9216);             //   262144
  u8*   h80    = (u8*)(wsb + 271360);            //   131072  (memset 0..402432)
  u16*  hb1    = (u16*)(wsb + 402432);           //   262144
  u8*   h81    = (u8*)(wsb + 664576);            //   131072
  float* den   = (float*)(wsb + 795648);         //      512
  u8*   mask8  = (u8*)(wsb + 796160);            //  8388608  [t][b][f]
  u16*  beta   = (u16*)(wsb + 9184768);          // 16777216  [t][b][f]
  u16*  gammah = (u16*)(wsb + 25961984);         // 33554432  [t][b][h]
  u16*  Whist  = (u16*)(wsb + 59516416);         //   262144
  u16*  Wfr    = (u16*)(wsb + 59778560);         //   131072
  u16*  Wgh    = (u16*)(wsb + 59909632);         //   262144
  u16*  Wcomb  = (u16*)(wsb + 60171776);         //   262144
  u8*   Wih8   = (u8*)(wsb + 60433920);          //  1048576
  u8*   Whh8   = (u8*)(wsb + 61482496);          //  1048576  -> 62531072 total

  // zero flags, xcc, num, hb0, h80 on every (graph-replayed) call
  hipMemsetAsync(d_ws, 0, 402432, stream);

  k_conv<<<dim3((CV_TOT+255)/256), dim3(256), 0, stream>>>(
      (const float*)d_in[3], (const float*)d_in[7], (const float*)d_in[9],
      (const float*)d_in[11], Wgh, Whist, Wfr, Wcomb);
  k_conv8<<<dim3(4096), dim3(256), 0, stream>>>(
      (const float*)d_in[13], (const float*)d_in[15], Wih8, Whh8);
  k_den<<<dim3(128), dim3(256), 0, stream>>>((const float*)d_in[1], den, mask8);

  P p{};
  p.x = (const float*)d_in[0];  p.mask = (const float*)d_in[1];
  p.deltas = (const float*)d_in[2];
  p.b_gh = (const float*)d_in[4];  p.w_gx = (const float*)d_in[5];
  p.b_gx = (const float*)d_in[6];  p.b_comb = (const float*)d_in[12];
  p.Wgh = Wgh; p.Wcomb = Wcomb;
  p.gammah = gammah; p.beta = beta;
  gk<M_GH><<<dim3(8, 512), dim3(256), 0, stream>>>(p);    // gamma_h, all t
  gk<M_BETA><<<dim3(4, 512), dim3(256), 0, stream>>>(p);  // beta, all t

  PSP ps{};
  ps.x = (const float*)d_in[0];  ps.mask = (const float*)d_in[1];
  ps.b_hist = (const float*)d_in[8];  ps.b_fr = (const float*)d_in[10];
  ps.b_ih = (const float*)d_in[14];   ps.b_hh = (const float*)d_in[16];
  ps.Whist = Whist; ps.Wfr = Wfr; ps.gammah = gammah; ps.beta = beta;
  ps.Wih8 = Wih8; ps.Whh8 = Whh8; ps.mask8 = mask8;
  ps.hb0 = hb0; ps.hb1 = hb1; ps.h80 = h80; ps.h81 = h81;
  ps.num = num; ps.out = (float*)d_out;
  ps.flags = flags; ps.xcc = xcc;
  k_loopP<<<dim3(128), dim3(512), 0, stream>>>(ps);

  k_final<<<dim3(1), dim3(64), 0, stream>>>(num, den, (float*)d_out);
}

// Round 13
// 4915.198 us; speedup vs baseline: 1.8463x; 1.0269x over previous
//
#include <hip/hip_runtime.h>
#include <hip/hip_bf16.h>

typedef float f32x4 __attribute__((ext_vector_type(4)));
typedef __bf16 bf16x8 __attribute__((ext_vector_type(8)));
typedef short s16x8 __attribute__((ext_vector_type(8)));
typedef unsigned short u16;
typedef unsigned long long u64;
typedef unsigned char u8;

constexpr int Bb = 256, Tt = 128, Ff = 256, Hh = 512;
constexpr int TF = Tt * Ff;                       // 32768
constexpr long OFF_RECON = (long)Bb * Tt * Ff;    // 8388608
constexpr long OFF_H     = 2L * Bb * Tt * Ff;     // 16777216
constexpr long OFF_LOSS  = OFF_H + (long)Bb * Hh; // 16908288

__device__ inline float sigf(float v){ return 1.f / (1.f + expf(-v)); }
__device__ inline u16 f2b(float f){
  unsigned u = __float_as_uint(f);
  u += 0x7fffu + ((u >> 16) & 1u);   // RNE
  return (u16)(u >> 16);
}
__device__ inline float b2f(u16 b){ return __uint_as_float(((unsigned)b) << 16); }

// ---- fp8 e4m3 (OCP) conversion ----
__device__ inline unsigned f2e4_sw(float f){
  unsigned u = __float_as_uint(f);
  unsigned s = (u >> 24) & 0x80u;
  int e = (int)((u >> 23) & 0xff) - 127;
  unsigned m = u & 0x7fffffu;
  if (((u >> 23) & 0xff) == 0xff) return s | 0x7e;
  if (e > 8 || (e == 8 && m > 0x600000)) return s | 0x7e;
  if (e < -10) return s;
  if (e >= -6) {
    unsigned keep = m >> 20, rest = m & 0xfffffu;
    keep += (rest > 0x80000u) || (rest == 0x80000u && (keep & 1));
    unsigned ee = (unsigned)(e + 7);
    if (keep == 8) { keep = 0; ee += 1; }
    if (ee >= 16) return s | 0x7e;
    return s | (ee << 3) | keep;
  }
  unsigned full = (1u << 23) | m;
  int shift = 20 + (-6 - e);
  unsigned keep = full >> shift;
  unsigned rest = full & ((1u << shift) - 1u);
  unsigned half = 1u << (shift - 1);
  keep += (rest > half) || (rest == half && (keep & 1));
  return s | keep;
}
__device__ inline unsigned f2e4(float f){
#if __has_builtin(__builtin_amdgcn_cvt_pk_fp8_f32)
  return (unsigned)__builtin_amdgcn_cvt_pk_fp8_f32(f, f, 0, false) & 0xffu;
#else
  return f2e4_sw(f);
#endif
}
__device__ inline unsigned pk2e4(float a, float b){
#if __has_builtin(__builtin_amdgcn_cvt_pk_fp8_f32)
  return (unsigned)__builtin_amdgcn_cvt_pk_fp8_f32(a, b, 0, false) & 0xffffu;
#else
  return f2e4_sw(a) | (f2e4_sw(b) << 8);
#endif
}

__device__ inline f32x4 mfma16(bf16x8 a, bf16x8 b, f32x4 c){
  return __builtin_amdgcn_mfma_f32_16x16x32_bf16(a, b, c, 0, 0, 0);
}
__device__ inline f32x4 mfma8(u64 a, u64 b, f32x4 c){
  return __builtin_amdgcn_mfma_f32_16x16x32_fp8_fp8((long)a, (long)b, c, 0, 0, 0);
}
__device__ inline bf16x8 ldb8(const u16* p){ return *reinterpret_cast<const bf16x8*>(p); }
__device__ inline bf16x8 cvt8(const float* p){
  const float4 a = ((const float4*)p)[0], b = ((const float4*)p)[1];
  s16x8 r;
  r[0]=f2b(a.x); r[1]=f2b(a.y); r[2]=f2b(a.z); r[3]=f2b(a.w);
  r[4]=f2b(b.x); r[5]=f2b(b.y); r[6]=f2b(b.z); r[7]=f2b(b.w);
  return __builtin_bit_cast(bf16x8, r);
}

// ---------------- hoisted big GEMMs (gamma_h, beta for all t; [t][b] layout) ----------------
enum { M_GH, M_BETA };

struct P {
  const float *x, *mask, *deltas;
  const float *b_gh, *w_gx, *b_gx, *b_comb;
  const u16 *Wgh, *Wcomb;
  u16 *gammah, *beta;
};

template<int MODE>
__global__ __launch_bounds__(256) void gk(P p)
{
  constexpr int K = (MODE==M_GH) ? 256 : 512;
  const int lane = threadIdx.x & 63;
  const int w = threadIdx.x >> 6;
  const int m0 = blockIdx.y*64 + (w>>1)*32;
  const int n0 = blockIdx.x*64 + (w&1)*32;
  const int fr = lane & 15;
  const int kg = (lane >> 4) << 3;

  f32x4 acc[2][2] = {};
  for (int k = 0; k < K; k += 32) {
    const int kk = k + kg;
    bf16x8 a[2], b[2];
    #pragma unroll
    for (int r = 0; r < 2; ++r) {
      const int mr = m0 + 16*r + fr;
      if constexpr (MODE == M_GH) {
        a[r] = cvt8(p.deltas + (size_t)mr*256 + kk);
      } else {
        if (kk < 256) {
          const float4 d0 = *(const float4*)(p.deltas + (size_t)mr*256 + kk);
          const float4 d1 = *(const float4*)(p.deltas + (size_t)mr*256 + kk + 4);
          const float4 w0 = *(const float4*)(p.w_gx + kk);
          const float4 w1 = *(const float4*)(p.w_gx + kk + 4);
          const float4 g0 = *(const float4*)(p.b_gx + kk);
          const float4 g1 = *(const float4*)(p.b_gx + kk + 4);
          s16x8 v;
          v[0]=f2b(expf(-fmaxf(d0.x*w0.x+g0.x,0.f)));
          v[1]=f2b(expf(-fmaxf(d0.y*w0.y+g0.y,0.f)));
          v[2]=f2b(expf(-fmaxf(d0.z*w0.z+g0.z,0.f)));
          v[3]=f2b(expf(-fmaxf(d0.w*w0.w+g0.w,0.f)));
          v[4]=f2b(expf(-fmaxf(d1.x*w1.x+g1.x,0.f)));
          v[5]=f2b(expf(-fmaxf(d1.y*w1.y+g1.y,0.f)));
          v[6]=f2b(expf(-fmaxf(d1.z*w1.z+g1.z,0.f)));
          v[7]=f2b(expf(-fmaxf(d1.w*w1.w+g1.w,0.f)));
          a[r] = __builtin_bit_cast(bf16x8, v);
        } else {
          a[r] = cvt8(p.mask + (size_t)mr*256 + (kk-256));
        }
      }
    }
    #pragma unroll
    for (int cc = 0; cc < 2; ++cc) {
      const int nr = n0 + 16*cc + fr;
      if constexpr (MODE == M_GH) b[cc] = ldb8(p.Wgh   + (size_t)nr*256 + kk);
      else                        b[cc] = ldb8(p.Wcomb + (size_t)nr*512 + kk);
    }
    #pragma unroll
    for (int r = 0; r < 2; ++r)
      #pragma unroll
      for (int cc = 0; cc < 2; ++cc)
        acc[r][cc] = mfma16(a[r], b[cc], acc[r][cc]);
  }

  #pragma unroll
  for (int r = 0; r < 2; ++r)
    #pragma unroll
    for (int cc = 0; cc < 2; ++cc)
      #pragma unroll
      for (int q = 0; q < 4; ++q) {
        const int m = m0 + 16*r + (lane>>4)*4 + q;   // m = b*128 + t
        const int n = n0 + 16*cc + (lane&15);
        const size_t tb = (size_t)(m & 127)*256 + (m >> 7);   // [t][b]
        if constexpr (MODE == M_GH) {
          float v = expf(-fmaxf(acc[r][cc][q] + p.b_gh[n], 0.f));
          p.gammah[tb*512 + n] = f2b(v);
        } else {
          float v = sigf(acc[r][cc][q] + p.b_comb[n]);
          p.beta[tb*256 + n] = f2b(v);
        }
      }
}

// ---------------- weight conversion / den / final ----------------
constexpr int CV_TOT = 131072+131072+65536+131072; // bf16 ones
__global__ __launch_bounds__(256) void k_conv(
    const float* Wgh, const float* Whist, const float* Wfr, const float* Wcomb,
    u16* ogh, u16* ohist, u16* ofr, u16* ocomb)
{
  int i = blockIdx.x*256 + threadIdx.x;
  if (i >= CV_TOT) return;
  int j = i;
  if (j < 131072) { ogh[j] = f2b(Wgh[j]); return; }       j -= 131072;
  if (j < 131072) { ohist[j] = f2b(Whist[j]); return; }   j -= 131072;
  if (j < 65536)  { ofr[j] = ((j>>8)==(j&255)) ? (u16)0 : f2b(Wfr[j]); return; } j -= 65536;
  ocomb[j] = f2b(Wcomb[j]);
}

__global__ __launch_bounds__(256) void k_conv8(
    const float* Wih, const float* Whh, u8* oih, u8* ohh)
{
  int i = blockIdx.x*256 + threadIdx.x;   // pair index, total 1048576
  if (i < 524288) {
    ((u16*)oih)[i] = (u16)pk2e4(Wih[2*i], Wih[2*i+1]);
  } else {
    int j = i - 524288;
    ((u16*)ohh)[j] = (u16)pk2e4(Whh[2*j], Whh[2*j+1]);
  }
}

__global__ __launch_bounds__(256) void k_den(const float* __restrict__ mask,
                                             float* den, u8* mask8)
{
  const int t = blockIdx.x;
  const int f = threadIdx.x;
  float s = 0.f;
  for (int b = 0; b < Bb; ++b) {
    float mv = mask[(size_t)b*TF + (size_t)t*256 + f];
    s += mv;
    mask8[((size_t)t*256 + b)*256 + f] = (u8)f2e4(mv);
  }
  __shared__ float red[4];
  #pragma unroll
  for (int o = 32; o; o >>= 1) s += __shfl_down(s, o);
  if ((f & 63) == 0) red[f >> 6] = s;
  __syncthreads();
  if (f == 0) den[t] = red[0]+red[1]+red[2]+red[3];
}

__global__ void k_final(const float* num, const float* den, float* out)
{
  if (threadIdx.x < 64) {
    int t = threadIdx.x;
    float s = num[t]/(den[t]+1e-12f) + num[t+64]/(den[t+64]+1e-12f);
    #pragma unroll
    for (int o = 32; o; o >>= 1) s += __shfl_down(s, o);
    if (t == 0) { out[OFF_LOSS] = s; out[OFF_LOSS+1] = 0.f; }
  }
}

// ---------------- persistent recurrence: 16 slabs x 8 cg-blocks, relaxed flag sync ----------------
struct PSP {
  const float *x, *mask;
  const float *b_hist, *b_fr, *b_ih, *b_hh;
  const u16 *Whist, *Wfr, *gammah, *beta;
  const u8 *Wih8, *Whh8, *mask8;
  u16 *hb0, *hb1; u8 *h80, *h81;     // parity double-buffered h (bf16 + fp8)
  float *num, *out;
  unsigned *flags; int *xcc;
};

// slab = bid&15 (16 rows); cg = bid>>4 (64 h-cols). Slab members on one XCD
// (runtime-verified). Fast path: plain h stores + vmcnt(0) + RELAXED flag;
// consumers poll RELAXED + read h via sc0 -> no L2 invalidate/writeback.
// Latency hiding: prefetch all h-independent streams BEFORE the flag wait;
// defer output stores past the flag publish; h8 loads in flight through A-part.
__global__ __launch_bounds__(512, 1) void k_loopP(PSP p)
{
  __shared__ char smem[22016];
  float* pre_s  = (float*)smem;           // [4][16][68] f32 (17408 B; aliases xr_s)
  u16*   xr_s   = (u16*)smem;             // [16][264] bf16 (8448 B)
  u8*    ximp_s = (u8*)(smem + 17408);    // [16][272] fp8 (4352 B)
  __shared__ int s_fast;

  const int tid = threadIdx.x, lane = tid & 63, w = tid >> 6;
  const int fr = lane & 15, kg = (lane >> 4) << 3;
  const int bid = blockIdx.x;
  const int slab = bid & 15, cg = bid >> 4;
  const int m0 = slab*16, hc0 = cg*64;

  // publish XCC id; decide fast (same-XCD slab) path
  if (tid == 0) {
    unsigned xv;
    asm volatile("s_getreg_b32 %0, hwreg(HW_REG_XCC_ID)" : "=s"(xv));
    __hip_atomic_store(p.xcc + bid, (int)(xv & 15u) + 1, __ATOMIC_RELAXED, __HIP_MEMORY_SCOPE_AGENT);
    int v0 = 0, ok = 1;
    #pragma unroll 1
    for (int j = 0; j < 8; ++j) {
      int v; unsigned spin = 0;
      do {
        v = __hip_atomic_load(p.xcc + slab + 16*j, __ATOMIC_RELAXED, __HIP_MEMORY_SCOPE_AGENT);
        if (v) break;
        __builtin_amdgcn_s_sleep(8);
      } while (++spin < (1u<<22));
      if (j == 0) v0 = v;
      ok &= (v != 0) && (v == v0);
    }
    s_fast = ok;
  }
  __syncthreads();
  const int fast = s_fast;

  // hoisted per-lane biases
  const int nA0 = w * 32;
  float bh[2], bf2[2];
  #pragma unroll
  for (int cc = 0; cc < 2; ++cc) {
    bh[cc]  = p.b_hist[nA0 + cc*16 + fr];
    bf2[cc] = p.b_fr  [nA0 + cc*16 + fr];
  }
  const int gB = w >> 1, half = w & 1;        // B-part wave roles
  const int lrow = tid >> 5, lcolp = (tid & 31) * 2;
  float bsum[4][2];
  #pragma unroll
  for (int g = 0; g < 4; ++g)
    #pragma unroll
    for (int j = 0; j < 2; ++j) {
      const int n = hc0 + lcolp + j;
      bsum[g][j] = p.b_ih[g*512 + n] + p.b_hh[g*512 + n];
    }
  float c0 = 0.f, c1 = 0.f;

  for (int t = 0; t < Tt; ++t) {
    const u16* hr  = (t & 1) ? p.hb1 : p.hb0;
    u16*       hw  = (t & 1) ? p.hb0 : p.hb1;
    const u8*  h8r = (t & 1) ? p.h81 : p.h80;
    u8*        h8w = (t & 1) ? p.h80 : p.h81;

    // ===== prefetch ALL recurrence-independent data for this step (pre-wait) =====
    float mmv[8], xxv[8]; u16 betv[8];
    #pragma unroll
    for (int cc = 0; cc < 2; ++cc)
      #pragma unroll
      for (int q = 0; q < 4; ++q) {
        const int e = cc*4 + q;
        const int row = (lane>>4)*4 + q;
        const int n   = nA0 + cc*16 + fr;
        const size_t gi = (size_t)(m0+row)*TF + (size_t)t*256 + n;
        xxv[e] = p.x[gi];
        mmv[e] = p.mask[gi];
        betv[e] = p.beta[((size_t)t*256 + m0+row)*256 + n];
      }
    unsigned gnw = 0;
    if (t < Tt-1)
      gnw = *(const unsigned*)(p.gammah + ((size_t)(t+1)*256 + m0 + lrow)*512 + hc0 + lcolp);

    // ===== wait for all slab members to finish step t-1 =====
    if (t > 0) {
      if (w == 0 && lane < 8) {
        const unsigned tgt = (unsigned)t;
        unsigned* mf = p.flags + (size_t)(slab + 16*lane)*16;
        unsigned spin = 0;
        if (fast) {
          while (__hip_atomic_load(mf, __ATOMIC_RELAXED, __HIP_MEMORY_SCOPE_AGENT) < tgt
                 && spin < (1u<<24)) { __builtin_amdgcn_s_sleep(8); ++spin; }
        } else {
          while (__hip_atomic_load(mf, __ATOMIC_ACQUIRE, __HIP_MEMORY_SCOPE_AGENT) < tgt
                 && spin < (1u<<24)) { __builtin_amdgcn_s_sleep(8); ++spin; }
        }
      }
      __syncthreads();
      __builtin_amdgcn_sched_barrier(0);
    }

    // ===== h loads: bf16 (sc0) drain, then fp8 fire-and-fly through A-part =====
    bf16x8 ah[16];
    {
      const u16* hb = hr + (size_t)(m0 + fr)*512 + kg;
      #pragma unroll
      for (int i = 0; i < 16; ++i) {
        const u16* pa = hb + i*32;
        asm volatile("global_load_dwordx4 %0, %1, off sc0" : "=&v"(ah[i]) : "v"(pa));
      }
      asm volatile("s_waitcnt vmcnt(0)" ::: "memory");
      __builtin_amdgcn_sched_barrier(0);
    }
    u64 a8[16];
    {
      const u8* h8b = h8r + (size_t)(m0 + fr)*512 + kg;
      #pragma unroll
      for (int i = 0; i < 16; ++i) {
        const u8* pa = h8b + i*32;
        asm volatile("global_load_dwordx2 %0, %1, off sc0" : "=&v"(a8[i]) : "v"(pa));
      }
    }

    // ===== A-part: XH (K=512) -> xr(LDS) -> XU (K=256) =====
    f32x4 acc[2] = {};
    #pragma unroll
    for (int k = 0; k < 16; ++k) {
      #pragma unroll
      for (int cc = 0; cc < 2; ++cc)
        acc[cc] = mfma16(ah[k], ldb8(p.Whist + (size_t)(nA0 + cc*16 + fr)*512 + k*32 + kg), acc[cc]);
    }
    float xhv[8];
    #pragma unroll
    for (int cc = 0; cc < 2; ++cc)
      #pragma unroll
      for (int q = 0; q < 4; ++q) {
        const int e = cc*4 + q;
        const int row = (lane>>4)*4 + q;          // 0..15
        const int n   = nA0 + cc*16 + fr;
        const float v = acc[cc][q] + bh[cc];
        xhv[e] = v;
        xr_s[row*264 + n] = f2b(mmv[e]*xxv[e] + (1.f-mmv[e])*v);
      }
    __syncthreads();

    f32x4 acc2[2] = {};
    #pragma unroll
    for (int k = 0; k < 8; ++k) {
      bf16x8 a = *(const bf16x8*)(xr_s + fr*264 + k*32 + kg);
      #pragma unroll
      for (int cc = 0; cc < 2; ++cc)
        acc2[cc] = mfma16(a, ldb8(p.Wfr + (size_t)(nA0 + cc*16 + fr)*256 + k*32 + kg), acc2[cc]);
    }
    float xcv[8], xiv[8], lnum = 0.f;
    #pragma unroll
    for (int cc = 0; cc < 2; ++cc)
      #pragma unroll
      for (int q = 0; q < 4; ++q) {
        const int e = cc*4 + q;
        const int row = (lane>>4)*4 + q;
        const int n   = nA0 + cc*16 + fr;
        const float xu  = acc2[cc][q] + bf2[cc];
        const float bet = b2f(betv[e]);
        const float xc  = bet*xu + (1.f-bet)*xhv[e];
        const float xi  = mmv[e]*xxv[e] + (1.f-mmv[e])*xc;
        ximp_s[row*272 + n] = (u8)f2e4(xi);
        xcv[e] = xc; xiv[e] = xi;                 // deferred stores
        lnum += fabsf(xc - xxv[e])*mmv[e];
      }
    if (cg == 0) {
      #pragma unroll
      for (int o = 32; o; o >>= 1) lnum += __shfl_down(lnum, o);
      if (lane == 0) atomicAdd(p.num + t, lnum);
    }
    __syncthreads();   // xr_s dead; ximp_s ready

    // ===== B-part: fp8 gates (K=1024); wave = (gate, col-half) =====
    f32x4 ag[2] = {};
    #pragma unroll
    for (int k = 0; k < 8; ++k) {         // K 0..256: x_imp fp8 (LDS)
      const u64 a = *(const u64*)(ximp_s + (size_t)fr*272 + k*32 + kg);
      #pragma unroll
      for (int cc = 0; cc < 2; ++cc)
        ag[cc] = mfma8(a, *(const u64*)(p.Wih8 + (size_t)(gB*512 + hc0 + half*32 + cc*16 + fr)*512 + k*32 + kg), ag[cc]);
    }
    #pragma unroll
    for (int k = 0; k < 8; ++k) {         // K 256..512: mask fp8
      const u64 a = *(const u64*)(p.mask8 + ((size_t)t*256 + m0 + fr)*256 + k*32 + kg);
      #pragma unroll
      for (int cc = 0; cc < 2; ++cc)
        ag[cc] = mfma8(a, *(const u64*)(p.Wih8 + (size_t)(gB*512 + hc0 + half*32 + cc*16 + fr)*512 + 256 + k*32 + kg), ag[cc]);
    }
    asm volatile("s_waitcnt vmcnt(0)" ::: "memory");
    __builtin_amdgcn_sched_barrier(0);
    #pragma unroll
    for (int k = 0; k < 16; ++k) {        // K 512..1024: h_dec fp8 (registers)
      #pragma unroll
      for (int cc = 0; cc < 2; ++cc)
        ag[cc] = mfma8(a8[k], *(const u64*)(p.Whh8 + (size_t)(gB*512 + hc0 + half*32 + cc*16 + fr)*512 + k*32 + kg), ag[cc]);
    }
    #pragma unroll
    for (int cc = 0; cc < 2; ++cc)
      #pragma unroll
      for (int q = 0; q < 4; ++q) {
        const int row = (lane>>4)*4 + q;
        const int col = half*32 + cc*16 + fr;
        pre_s[(gB*16 + row)*68 + col] = ag[cc][q];
      }
    __syncthreads();

    // ===== fused LSTM: thread owns (lrow, 2 cols); c in registers =====
    {
      float hvv[2];
      {
        const float pi = pre_s[(0*16 + lrow)*68 + lcolp] + bsum[0][0];
        const float pf = pre_s[(1*16 + lrow)*68 + lcolp] + bsum[1][0];
        const float pg = pre_s[(2*16 + lrow)*68 + lcolp] + bsum[2][0];
        const float po = pre_s[(3*16 + lrow)*68 + lcolp] + bsum[3][0];
        const float cv = sigf(pf)*c0 + sigf(pi)*tanhf(pg);
        c0 = cv; hvv[0] = sigf(po)*tanhf(cv);
      }
      {
        const float pi = pre_s[(0*16 + lrow)*68 + lcolp+1] + bsum[0][1];
        const float pf = pre_s[(1*16 + lrow)*68 + lcolp+1] + bsum[1][1];
        const float pg = pre_s[(2*16 + lrow)*68 + lcolp+1] + bsum[2][1];
        const float po = pre_s[(3*16 + lrow)*68 + lcolp+1] + bsum[3][1];
        const float cv = sigf(pf)*c1 + sigf(pi)*tanhf(pg);
        c1 = cv; hvv[1] = sigf(po)*tanhf(cv);
      }
      const int idx0 = (m0+lrow)*512 + hc0 + lcolp;
      if (t == Tt-1) {
        __builtin_nontemporal_store(hvv[0], p.out + OFF_H + idx0);
        __builtin_nontemporal_store(hvv[1], p.out + OFF_H + idx0 + 1);
      } else {
        const float gn0 = b2f((u16)(gnw & 0xffffu));
        const float gn1 = b2f((u16)(gnw >> 16));
        const float hd0 = hvv[0]*gn0, hd1 = hvv[1]*gn1;
        union { unsigned u; u16 h[2]; } pb2;
        pb2.h[0] = f2b(hd0); pb2.h[1] = f2b(hd1);
        *(unsigned*)(hw + idx0) = pb2.u;            // plain: write-through to L2
        *(u16*)(h8w + idx0) = (u16)pk2e4(hd0, hd1);
      }
    }

    // ===== publish step completion (h stores only on the drain) =====
    if (t < Tt-1) {
      asm volatile("s_waitcnt vmcnt(0)" ::: "memory");
      __syncthreads();
      if (tid == 0) {
        if (fast)
          __hip_atomic_store(p.flags + (size_t)bid*16, (unsigned)(t+1),
                             __ATOMIC_RELAXED, __HIP_MEMORY_SCOPE_AGENT);
        else
          __hip_atomic_store(p.flags + (size_t)bid*16, (unsigned)(t+1),
                             __ATOMIC_RELEASE, __HIP_MEMORY_SCOPE_AGENT);
      }
    }

    // ===== deferred output stores (off the inter-step critical path) =====
    if (cg == 0) {
      #pragma unroll
      for (int cc = 0; cc < 2; ++cc)
        #pragma unroll
        for (int q = 0; q < 4; ++q) {
          const int e = cc*4 + q;
          const int row = (lane>>4)*4 + q;
          const int n   = nA0 + cc*16 + fr;
          const size_t gi = (size_t)(m0+row)*TF + (size_t)t*256 + n;
          __builtin_nontemporal_store(xcv[e], p.out + OFF_RECON + gi);
          __builtin_nontemporal_store(xiv[e], p.out + gi);
        }
    }
  }
}

extern "C" void kernel_launch(void* const* d_in, const int* in_sizes, int n_in,
                              void* d_out, int out_size, void* d_ws, size_t ws_size,
                              hipStream_t stream)
{
  char* wsb = (char*)d_ws;
  unsigned* flags = (unsigned*)(wsb + 0);        //     8192 (128 x 64B)
  int*      xcc   = (int*)(wsb + 8192);          //      512
  float*    num   = (float*)(wsb + 8704);        //      512
  u16*  hb0    = (u16*)(wsb + 9216);             //   262144
  u8*   h80    = (u8*)(wsb + 271360);            //   131072  (memset 0..402432)
  u16*  hb1    = (u16*)(wsb + 402432);           //   262144
  u8*   h81    = (u8*)(wsb + 664576);            //   131072
  float* den   = (float*)(wsb + 795648);         //      512
  u8*   mask8  = (u8*)(wsb + 796160);            //  8388608  [t][b][f]
  u16*  beta   = (u16*)(wsb + 9184768);          // 16777216  [t][b][f]
  u16*  gammah = (u16*)(wsb + 25961984);         // 33554432  [t][b][h]
  u16*  Whist  = (u16*)(wsb + 59516416);         //   262144
  u16*  Wfr    = (u16*)(wsb + 59778560);         //   131072
  u16*  Wgh    = (u16*)(wsb + 59909632);         //   262144
  u16*  Wcomb  = (u16*)(wsb + 60171776);         //   262144
  u8*   Wih8   = (u8*)(wsb + 60433920);          //  1048576
  u8*   Whh8   = (u8*)(wsb + 61482496);          //  1048576  -> 62531072 total

  // zero flags, xcc, num, hb0, h80 on every (graph-replayed) call
  hipMemsetAsync(d_ws, 0, 402432, stream);

  k_conv<<<dim3((CV_TOT+255)/256), dim3(256), 0, stream>>>(
      (const float*)d_in[3], (const float*)d_in[7], (const float*)d_in[9],
      (const float*)d_in[11], Wgh, Whist, Wfr, Wcomb);
  k_conv8<<<dim3(4096), dim3(256), 0, stream>>>(
      (const float*)d_in[13], (const float*)d_in[15], Wih8, Whh8);
  k_den<<<dim3(128), dim3(256), 0, stream>>>((const float*)d_in[1], den, mask8);

  P p{};
  p.x = (const float*)d_in[0];  p.mask = (const float*)d_in[1];
  p.deltas = (const float*)d_in[2];
  p.b_gh = (const float*)d_in[4];  p.w_gx = (const float*)d_in[5];
  p.b_gx = (const float*)d_in[6];  p.b_comb = (const float*)d_in[12];
  p.Wgh = Wgh; p.Wcomb = Wcomb;
  p.gammah = gammah; p.beta = beta;
  gk<M_GH><<<dim3(8, 512), dim3(256), 0, stream>>>(p);    // gamma_h, all t
  gk<M_BETA><<<dim3(4, 512), dim3(256), 0, stream>>>(p);  // beta, all t

  PSP ps{};
  ps.x = (const float*)d_in[0];  ps.mask = (const float*)d_in[1];
  ps.b_hist = (const float*)d_in[8];  ps.b_fr = (const float*)d_in[10];
  ps.b_ih = (const float*)d_in[14];   ps.b_hh = (const float*)d_in[16];
  ps.Whist = Whist; ps.Wfr = Wfr; ps.gammah = gammah; ps.beta = beta;
  ps.Wih8 = Wih8; ps.Whh8 = Whh8; ps.mask8 = mask8;
  ps.hb0 = hb0; ps.hb1 = hb1; ps.h80 = h80; ps.h81 = h81;
  ps.num = num; ps.out = (float*)d_out;
  ps.flags = flags; ps.xcc = xcc;
  k_loopP<<<dim3(128), dim3(512), 0, stream>>>(ps);

  k_final<<<dim3(1), dim3(64), 0, stream>>>(num, den, (float*)d_out);
}

// Round 14
// 4886.153 us; speedup vs baseline: 1.8572x; 1.0059x over previous
//
#include <hip/hip_runtime.h>
#include <hip/hip_bf16.h>

typedef float f32x4 __attribute__((ext_vector_type(4)));
typedef __bf16 bf16x8 __attribute__((ext_vector_type(8)));
typedef short s16x8 __attribute__((ext_vector_type(8)));
typedef unsigned short u16;
typedef unsigned long long u64;
typedef unsigned char u8;

constexpr int Bb = 256, Tt = 128, Ff = 256, Hh = 512;
constexpr int TF = Tt * Ff;                       // 32768
constexpr long OFF_RECON = (long)Bb * Tt * Ff;    // 8388608
constexpr long OFF_H     = 2L * Bb * Tt * Ff;    // 16777216
constexpr long OFF_LOSS  = OFF_H + (long)Bb * Hh; // 16908288

__device__ inline float sigf(float v){ return 1.f / (1.f + expf(-v)); }
__device__ inline u16 f2b(float f){
  unsigned u = __float_as_uint(f);
  u += 0x7fffu + ((u >> 16) & 1u);   // RNE
  return (u16)(u >> 16);
}
__device__ inline float b2f(u16 b){ return __uint_as_float(((unsigned)b) << 16); }

// ---- fp8 e4m3 (OCP) conversion ----
__device__ inline unsigned f2e4_sw(float f){
  unsigned u = __float_as_uint(f);
  unsigned s = (u >> 24) & 0x80u;
  int e = (int)((u >> 23) & 0xff) - 127;
  unsigned m = u & 0x7fffffu;
  if (((u >> 23) & 0xff) == 0xff) return s | 0x7e;
  if (e > 8 || (e == 8 && m > 0x600000)) return s | 0x7e;
  if (e < -10) return s;
  if (e >= -6) {
    unsigned keep = m >> 20, rest = m & 0xfffffu;
    keep += (rest > 0x80000u) || (rest == 0x80000u && (keep & 1));
    unsigned ee = (unsigned)(e + 7);
    if (keep == 8) { keep = 0; ee += 1; }
    if (ee >= 16) return s | 0x7e;
    return s | (ee << 3) | keep;
  }
  unsigned full = (1u << 23) | m;
  int shift = 20 + (-6 - e);
  unsigned keep = full >> shift;
  unsigned rest = full & ((1u << shift) - 1u);
  unsigned half = 1u << (shift - 1);
  keep += (rest > half) || (rest == half && (keep & 1));
  return s | keep;
}
__device__ inline unsigned f2e4(float f){
#if __has_builtin(__builtin_amdgcn_cvt_pk_fp8_f32)
  return (unsigned)__builtin_amdgcn_cvt_pk_fp8_f32(f, f, 0, false) & 0xffu;
#else
  return f2e4_sw(f);
#endif
}
__device__ inline unsigned pk2e4(float a, float b){
#if __has_builtin(__builtin_amdgcn_cvt_pk_fp8_f32)
  return (unsigned)__builtin_amdgcn_cvt_pk_fp8_f32(a, b, 0, false) & 0xffffu;
#else
  return f2e4_sw(a) | (f2e4_sw(b) << 8);
#endif
}

__device__ inline f32x4 mfma16(bf16x8 a, bf16x8 b, f32x4 c){
  return __builtin_amdgcn_mfma_f32_16x16x32_bf16(a, b, c, 0, 0, 0);
}
__device__ inline f32x4 mfma8(u64 a, u64 b, f32x4 c){
  return __builtin_amdgcn_mfma_f32_16x16x32_fp8_fp8((long)a, (long)b, c, 0, 0, 0);
}
__device__ inline bf16x8 ldb8(const u16* p){ return *reinterpret_cast<const bf16x8*>(p); }
__device__ inline bf16x8 cvt8(const float* p){
  const float4 a = ((const float4*)p)[0], b = ((const float4*)p)[1];
  s16x8 r;
  r[0]=f2b(a.x); r[1]=f2b(a.y); r[2]=f2b(a.z); r[3]=f2b(a.w);
  r[4]=f2b(b.x); r[5]=f2b(b.y); r[6]=f2b(b.z); r[7]=f2b(b.w);
  return __builtin_bit_cast(bf16x8, r);
}

// ---------------- hoisted big GEMMs (gamma_h, beta for all t; [t][b] layout) ----------------
enum { M_GH, M_BETA };

struct P {
  const float *x, *mask, *deltas;
  const float *b_gh, *w_gx, *b_gx, *b_comb;
  const u16 *Wgh, *Wcomb;
  u16 *gammah, *beta;
};

template<int MODE>
__global__ __launch_bounds__(256) void gk(P p)
{
  constexpr int K = (MODE==M_GH) ? 256 : 512;
  const int lane = threadIdx.x & 63;
  const int w = threadIdx.x >> 6;
  const int m0 = blockIdx.y*64 + (w>>1)*32;
  const int n0 = blockIdx.x*64 + (w&1)*32;
  const int fr = lane & 15;
  const int kg = (lane >> 4) << 3;

  f32x4 acc[2][2] = {};
  for (int k = 0; k < K; k += 32) {
    const int kk = k + kg;
    bf16x8 a[2], b[2];
    #pragma unroll
    for (int r = 0; r < 2; ++r) {
      const int mr = m0 + 16*r + fr;
      if constexpr (MODE == M_GH) {
        a[r] = cvt8(p.deltas + (size_t)mr*256 + kk);
      } else {
        if (kk < 256) {
          const float4 d0 = *(const float4*)(p.deltas + (size_t)mr*256 + kk);
          const float4 d1 = *(const float4*)(p.deltas + (size_t)mr*256 + kk + 4);
          const float4 w0 = *(const float4*)(p.w_gx + kk);
          const float4 w1 = *(const float4*)(p.w_gx + kk + 4);
          const float4 g0 = *(const float4*)(p.b_gx + kk);
          const float4 g1 = *(const float4*)(p.b_gx + kk + 4);
          s16x8 v;
          v[0]=f2b(expf(-fmaxf(d0.x*w0.x+g0.x,0.f)));
          v[1]=f2b(expf(-fmaxf(d0.y*w0.y+g0.y,0.f)));
          v[2]=f2b(expf(-fmaxf(d0.z*w0.z+g0.z,0.f)));
          v[3]=f2b(expf(-fmaxf(d0.w*w0.w+g0.w,0.f)));
          v[4]=f2b(expf(-fmaxf(d1.x*w1.x+g1.x,0.f)));
          v[5]=f2b(expf(-fmaxf(d1.y*w1.y+g1.y,0.f)));
          v[6]=f2b(expf(-fmaxf(d1.z*w1.z+g1.z,0.f)));
          v[7]=f2b(expf(-fmaxf(d1.w*w1.w+g1.w,0.f)));
          a[r] = __builtin_bit_cast(bf16x8, v);
        } else {
          a[r] = cvt8(p.mask + (size_t)mr*256 + (kk-256));
        }
      }
    }
    #pragma unroll
    for (int cc = 0; cc < 2; ++cc) {
      const int nr = n0 + 16*cc + fr;
      if constexpr (MODE == M_GH) b[cc] = ldb8(p.Wgh   + (size_t)nr*256 + kk);
      else                        b[cc] = ldb8(p.Wcomb + (size_t)nr*512 + kk);
    }
    #pragma unroll
    for (int r = 0; r < 2; ++r)
      #pragma unroll
      for (int cc = 0; cc < 2; ++cc)
        acc[r][cc] = mfma16(a[r], b[cc], acc[r][cc]);
  }

  #pragma unroll
  for (int r = 0; r < 2; ++r)
    #pragma unroll
    for (int cc = 0; cc < 2; ++cc)
      #pragma unroll
      for (int q = 0; q < 4; ++q) {
        const int m = m0 + 16*r + (lane>>4)*4 + q;   // m = b*128 + t
        const int n = n0 + 16*cc + (lane&15);
        const size_t tb = (size_t)(m & 127)*256 + (m >> 7);   // [t][b]
        if constexpr (MODE == M_GH) {
          float v = expf(-fmaxf(acc[r][cc][q] + p.b_gh[n], 0.f));
          p.gammah[tb*512 + n] = f2b(v);
        } else {
          float v = sigf(acc[r][cc][q] + p.b_comb[n]);
          p.beta[tb*256 + n] = f2b(v);
        }
      }
}

// ---------------- weight conversion / den / final ----------------
constexpr int CV_TOT = 131072+131072+65536+131072; // bf16 ones
__global__ __launch_bounds__(256) void k_conv(
    const float* Wgh, const float* Whist, const float* Wfr, const float* Wcomb,
    u16* ogh, u16* ohist, u16* ofr, u16* ocomb)
{
  int i = blockIdx.x*256 + threadIdx.x;
  if (i >= CV_TOT) return;
  int j = i;
  if (j < 131072) { ogh[j] = f2b(Wgh[j]); return; }       j -= 131072;
  if (j < 131072) { ohist[j] = f2b(Whist[j]); return; }   j -= 131072;
  if (j < 65536)  { ofr[j] = ((j>>8)==(j&255)) ? (u16)0 : f2b(Wfr[j]); return; } j -= 65536;
  ocomb[j] = f2b(Wcomb[j]);
}

__global__ __launch_bounds__(256) void k_conv8(
    const float* Wih, const float* Whh, u8* oih, u8* ohh)
{
  int i = blockIdx.x*256 + threadIdx.x;   // pair index, total 1048576
  if (i < 524288) {
    ((u16*)oih)[i] = (u16)pk2e4(Wih[2*i], Wih[2*i+1]);
  } else {
    int j = i - 524288;
    ((u16*)ohh)[j] = (u16)pk2e4(Whh[2*j], Whh[2*j+1]);
  }
}

__global__ __launch_bounds__(256) void k_den(const float* __restrict__ mask,
                                             float* den, u8* mask8)
{
  const int t = blockIdx.x;
  const int f = threadIdx.x;
  float s = 0.f;
  for (int b = 0; b < Bb; ++b) {
    float mv = mask[(size_t)b*TF + (size_t)t*256 + f];
    s += mv;
    mask8[((size_t)t*256 + b)*256 + f] = (u8)f2e4(mv);
  }
  __shared__ float red[4];
  #pragma unroll
  for (int o = 32; o; o >>= 1) s += __shfl_down(s, o);
  if ((f & 63) == 0) red[f >> 6] = s;
  __syncthreads();
  if (f == 0) den[t] = red[0]+red[1]+red[2]+red[3];
}

__global__ void k_final(const float* num, const float* den, float* out)
{
  if (threadIdx.x < 64) {
    int t = threadIdx.x;
    float s = num[t]/(den[t]+1e-12f) + num[t+64]/(den[t+64]+1e-12f);
    #pragma unroll
    for (int o = 32; o; o >>= 1) s += __shfl_down(s, o);
    if (t == 0) { out[OFF_LOSS] = s; out[OFF_LOSS+1] = 0.f; }
  }
}

// ---------------- persistent recurrence: 16 slabs x 8 cg-blocks, 1024 thr/block ----------------
struct PSP {
  const float *x, *mask;
  const float *b_hist, *b_fr, *b_ih, *b_hh;
  const u16 *Whist, *Wfr, *gammah, *beta;
  const u8 *Wih8, *Whh8, *mask8;
  u16 *hb0, *hb1; u8 *h80, *h81;     // parity double-buffered h (bf16 + fp8)
  float *num, *out;
  unsigned *flags; int *xcc;
};

// LDS (dynamic, 160640 B): whh_s [256][512] fp8 XOR-swizzled @0 (131072);
// h_s [16][520] bf16 @131072 (aliases pre_s [4][16][66] f32, region 16896);
// xr_s [16][264] bf16 @147968 (8448); ximp_s [16][264] fp8 @156416 (4224).
__global__ __launch_bounds__(1024, 4) void k_loopP(PSP p)
{
  extern __shared__ char smem[];
  u8*    whh_s  = (u8*)smem;
  u16*   h_s    = (u16*)(smem + 131072);
  float* pre_s  = (float*)(smem + 131072);
  u16*   xr_s   = (u16*)(smem + 147968);
  u8*    ximp_s = (u8*)(smem + 156416);
  __shared__ int s_fast;

  const int tid = threadIdx.x, lane = tid & 63, w = tid >> 6;
  const int fr = lane & 15, kg = (lane >> 4) << 3;
  const int bid = blockIdx.x;
  const int slab = bid & 15, cg = bid >> 4;
  const int m0 = slab*16, hc0 = cg*64;

  // publish XCC id; decide fast (same-XCD slab) path
  if (tid == 0) {
    unsigned xv;
    asm volatile("s_getreg_b32 %0, hwreg(HW_REG_XCC_ID)" : "=s"(xv));
    __hip_atomic_store(p.xcc + bid, (int)(xv & 15u) + 1, __ATOMIC_RELAXED, __HIP_MEMORY_SCOPE_AGENT);
    int v0 = 0, ok = 1;
    #pragma unroll 1
    for (int j = 0; j < 8; ++j) {
      int v; unsigned spin = 0;
      do {
        v = __hip_atomic_load(p.xcc + slab + 16*j, __ATOMIC_RELAXED, __HIP_MEMORY_SCOPE_AGENT);
        if (v) break;
        __builtin_amdgcn_s_sleep(8);
      } while (++spin < (1u<<22));
      if (j == 0) v0 = v;
      ok &= (v != 0) && (v == v0);
    }
    s_fast = ok;
  }

  // stage this block's Whh8 slice (4 gates x 64 cols x 512 K) into LDS, XOR-swizzled
  for (int i = tid; i < 8192; i += 1024) {
    const int row = i >> 5;                 // g*64 + c
    const int kk  = (i & 31) << 4;          // byte offset within 512B row
    const int g = row >> 6, c = row & 63;
    const float4 v = *(const float4*)(p.Whh8 + ((size_t)(g*512 + hc0 + c) << 9) + kk);
    *(float4*)(whh_s + ((size_t)row << 9) + (kk ^ ((row & 7) << 4))) = v;
  }
  __syncthreads();
  const int fast = s_fast;

  // hoisted per-lane constants
  const int nA0 = w * 16;                   // A-part: wave owns 16 cols
  const float bh  = p.b_hist[nA0 + fr];
  const float bfv = p.b_fr  [nA0 + fr];
  const int gB = w & 3, qh = w >> 2;        // B-part: wave = (gate, col-quarter)
  float bsum[4];
  #pragma unroll
  for (int g = 0; g < 4; ++g)
    bsum[g] = p.b_ih[g*512 + hc0 + lane] + p.b_hh[g*512 + hc0 + lane];
  float c0 = 0.f;

  for (int t = 0; t < Tt; ++t) {
    const u16* hr  = (t & 1) ? p.hb1 : p.hb0;
    u16*       hw  = (t & 1) ? p.hb0 : p.hb1;
    const u8*  h8r = (t & 1) ? p.h81 : p.h80;
    u8*        h8w = (t & 1) ? p.h80 : p.h81;

    // ===== prefetch recurrence-independent streams (pre-wait) =====
    float mmv[4], xxv[4]; u16 betv[4];
    #pragma unroll
    for (int q = 0; q < 4; ++q) {
      const int row = (lane>>4)*4 + q;
      const int n   = nA0 + fr;
      const size_t gi = (size_t)(m0+row)*TF + (size_t)t*256 + n;
      xxv[q] = p.x[gi];
      mmv[q] = p.mask[gi];
      betv[q] = p.beta[((size_t)t*256 + m0+row)*256 + n];
    }
    u16 gnv = 0;
    if (t < Tt-1)
      gnv = p.gammah[((size_t)(t+1)*256 + m0 + w)*512 + hc0 + lane];

    // ===== wait for slab members at step t-1 =====
    if (t > 0) {
      if (w == 0 && lane < 8) {
        const unsigned tgt = (unsigned)t;
        unsigned* mf = p.flags + (size_t)(slab + 16*lane)*16;
        unsigned spin = 0;
        if (fast) {
          while (__hip_atomic_load(mf, __ATOMIC_RELAXED, __HIP_MEMORY_SCOPE_AGENT) < tgt
                 && spin < (1u<<24)) { __builtin_amdgcn_s_sleep(8); ++spin; }
        } else {
          while (__hip_atomic_load(mf, __ATOMIC_ACQUIRE, __HIP_MEMORY_SCOPE_AGENT) < tgt
                 && spin < (1u<<24)) { __builtin_amdgcn_s_sleep(8); ++spin; }
        }
      }
      __syncthreads();
      __builtin_amdgcn_sched_barrier(0);
    }

    // ===== stage h(bf16) into LDS: wave w loads row w (sc0, L1-bypass) =====
    {
      bf16x8 hv;
      const u16* src = hr + (size_t)(m0 + w)*512 + lane*8;
      asm volatile("global_load_dwordx4 %0, %1, off sc0\n\ts_waitcnt vmcnt(0)"
                   : "=v"(hv) : "v"(src) : "memory");
      *(bf16x8*)(h_s + w*520 + lane*8) = hv;
    }
    __syncthreads();

    // ===== XH: x_h = h @ Whist^T (K=512), h from LDS =====
    f32x4 acc = {};
    #pragma unroll
    for (int k = 0; k < 16; ++k) {
      bf16x8 a = *(const bf16x8*)(h_s + fr*520 + k*32 + kg);
      bf16x8 b = ldb8(p.Whist + (size_t)(nA0 + fr)*512 + k*32 + kg);
      acc = mfma16(a, b, acc);
    }
    float xhv[4];
    #pragma unroll
    for (int q = 0; q < 4; ++q) {
      const int row = (lane>>4)*4 + q;
      const int n   = nA0 + fr;
      const float v = acc[q] + bh;
      xhv[q] = v;
      xr_s[row*264 + n] = f2b(mmv[q]*xxv[q] + (1.f-mmv[q])*v);
    }
    __syncthreads();

    // ===== XU: xu = xr @ Wfr_m^T (K=256) =====
    f32x4 acc2 = {};
    #pragma unroll
    for (int k = 0; k < 8; ++k) {
      bf16x8 a = *(const bf16x8*)(xr_s + fr*264 + k*32 + kg);
      bf16x8 b = ldb8(p.Wfr + (size_t)(nA0 + fr)*256 + k*32 + kg);
      acc2 = mfma16(a, b, acc2);
    }
    float xcv[4], xiv[4], lnum = 0.f;
    #pragma unroll
    for (int q = 0; q < 4; ++q) {
      const int row = (lane>>4)*4 + q;
      const int n   = nA0 + fr;
      const float xu  = acc2[q] + bfv;
      const float bet = b2f(betv[q]);
      const float xc  = bet*xu + (1.f-bet)*xhv[q];
      const float xi  = mmv[q]*xxv[q] + (1.f-mmv[q])*xc;
      ximp_s[row*264 + n] = (u8)f2e4(xi);
      xcv[q] = xc; xiv[q] = xi;
      lnum += fabsf(xc - xxv[q])*mmv[q];
    }
    if (cg == 0) {
      #pragma unroll
      for (int o = 32; o; o >>= 1) lnum += __shfl_down(lnum, o);
      if (lane == 0) atomicAdd(p.num + t, lnum);
    }
    __syncthreads();   // h_s dead (pre_s may overwrite); ximp_s ready

    // ===== B-part: fp8 gates (K=1024); wave = (gate gB, col-quarter qh) =====
    u64 a8[16];
    {
      const u8* h8b = h8r + (size_t)(m0 + fr)*512 + kg;
      #pragma unroll
      for (int i = 0; i < 16; ++i) {
        const u8* pa = h8b + i*32;
        asm volatile("global_load_dwordx2 %0, %1, off sc0" : "=&v"(a8[i]) : "v"(pa));
      }
    }
    f32x4 ag = {};
    #pragma unroll
    for (int k = 0; k < 8; ++k) {         // K 0..256: x_imp fp8 (LDS)
      const u64 a = *(const u64*)(ximp_s + (size_t)fr*264 + k*32 + kg);
      const u64 b = *(const u64*)(p.Wih8 + (size_t)(gB*512 + hc0 + qh*16 + fr)*512 + k*32 + kg);
      ag = mfma8(a, b, ag);
    }
    #pragma unroll
    for (int k = 0; k < 8; ++k) {         // K 256..512: mask fp8
      const u64 a = *(const u64*)(p.mask8 + ((size_t)t*256 + m0 + fr)*256 + k*32 + kg);
      const u64 b = *(const u64*)(p.Wih8 + (size_t)(gB*512 + hc0 + qh*16 + fr)*512 + 256 + k*32 + kg);
      ag = mfma8(a, b, ag);
    }
    asm volatile("s_waitcnt vmcnt(0)" ::: "memory");
    __builtin_amdgcn_sched_barrier(0);
    {
      const int wrow = gB*64 + qh*16 + fr;
      const int wsw  = (wrow & 7) << 4;
      #pragma unroll
      for (int k = 0; k < 16; ++k) {      // K 512..1024: h fp8 (regs) x Whh (LDS)
        const u64 b = *(const u64*)(whh_s + ((size_t)wrow << 9) + ((k*32 + kg) ^ wsw));
        ag = mfma8(a8[k], b, ag);
      }
    }
    #pragma unroll
    for (int q = 0; q < 4; ++q) {
      const int row = (lane>>4)*4 + q;
      pre_s[(gB*16 + row)*66 + qh*16 + fr] = ag[q];
    }
    __syncthreads();

    // ===== fused LSTM: thread owns exactly (row=w, col=lane) =====
    {
      const float pi = pre_s[(0*16 + w)*66 + lane] + bsum[0];
      const float pf = pre_s[(1*16 + w)*66 + lane] + bsum[1];
      const float pg = pre_s[(2*16 + w)*66 + lane] + bsum[2];
      const float po = pre_s[(3*16 + w)*66 + lane] + bsum[3];
      const float cv = sigf(pf)*c0 + sigf(pi)*tanhf(pg);
      c0 = cv;
      const float hv = sigf(po)*tanhf(cv);
      const int idx = (m0+w)*512 + hc0 + lane;
      if (t == Tt-1) {
        __builtin_nontemporal_store(hv, p.out + OFF_H + idx);
      } else {
        const float hd = hv * b2f(gnv);
        hw[idx]  = f2b(hd);                 // plain: write-through to local L2
        h8w[idx] = (u8)f2e4(hd);
      }
    }

    // ===== publish step completion =====
    if (t < Tt-1) {
      asm volatile("s_waitcnt vmcnt(0)" ::: "memory");
      __syncthreads();
      if (tid == 0) {
        if (fast)
          __hip_atomic_store(p.flags + (size_t)bid*16, (unsigned)(t+1),
                             __ATOMIC_RELAXED, __HIP_MEMORY_SCOPE_AGENT);
        else
          __hip_atomic_store(p.flags + (size_t)bid*16, (unsigned)(t+1),
                             __ATOMIC_RELEASE, __HIP_MEMORY_SCOPE_AGENT);
      }
    }

    // ===== deferred output stores (off the inter-step critical path) =====
    if (cg == 0) {
      #pragma unroll
      for (int q = 0; q < 4; ++q) {
        const int row = (lane>>4)*4 + q;
        const int n   = nA0 + fr;
        const size_t gi = (size_t)(m0+row)*TF + (size_t)t*256 + n;
        __builtin_nontemporal_store(xcv[q], p.out + OFF_RECON + gi);
        __builtin_nontemporal_store(xiv[q], p.out + gi);
      }
    }
  }
}

extern "C" void kernel_launch(void* const* d_in, const int* in_sizes, int n_in,
                              void* d_out, int out_size, void* d_ws, size_t ws_size,
                              hipStream_t stream)
{
  char* wsb = (char*)d_ws;
  unsigned* flags = (unsigned*)(wsb + 0);        //     8192 (128 x 64B)
  int*      xcc   = (int*)(wsb + 8192);          //      512
  float*    num   = (float*)(wsb + 8704);        //      512
  u16*  hb0    = (u16*)(wsb + 9216);             //   262144
  u8*   h80    = (u8*)(wsb + 271360);            //   131072  (memset 0..402432)
  u16*  hb1    = (u16*)(wsb + 402432);           //   262144
  u8*   h81    = (u8*)(wsb + 664576);            //   131072
  float* den   = (float*)(wsb + 795648);         //      512
  u8*   mask8  = (u8*)(wsb + 796160);            //  8388608  [t][b][f]
  u16*  beta   = (u16*)(wsb + 9184768);          // 16777216  [t][b][f]
  u16*  gammah = (u16*)(wsb + 25961984);         // 33554432  [t][b][h]
  u16*  Whist  = (u16*)(wsb + 59516416);         //   262144
  u16*  Wfr    = (u16*)(wsb + 59778560);         //   131072
  u16*  Wgh    = (u16*)(wsb + 59909632);         //   262144
  u16*  Wcomb  = (u16*)(wsb + 60171776);         //   262144
  u8*   Wih8   = (u8*)(wsb + 60433920);          //  1048576
  u8*   Whh8   = (u8*)(wsb + 61482496);          //  1048576  -> 62531072 total

  // zero flags, xcc, num, hb0, h80 on every (graph-replayed) call
  hipMemsetAsync(d_ws, 0, 402432, stream);

  k_conv<<<dim3((CV_TOT+255)/256), dim3(256), 0, stream>>>(
      (const float*)d_in[3], (const float*)d_in[7], (const float*)d_in[9],
      (const float*)d_in[11], Wgh, Whist, Wfr, Wcomb);
  k_conv8<<<dim3(4096), dim3(256), 0, stream>>>(
      (const float*)d_in[13], (const float*)d_in[15], Wih8, Whh8);
  k_den<<<dim3(128), dim3(256), 0, stream>>>((const float*)d_in[1], den, mask8);

  P p{};
  p.x = (const float*)d_in[0];  p.mask = (const float*)d_in[1];
  p.deltas = (const float*)d_in[2];
  p.b_gh = (const float*)d_in[4];  p.w_gx = (const float*)d_in[5];
  p.b_gx = (const float*)d_in[6];  p.b_comb = (const float*)d_in[12];
  p.Wgh = Wgh; p.Wcomb = Wcomb;
  p.gammah = gammah; p.beta = beta;
  gk<M_GH><<<dim3(8, 512), dim3(256), 0, stream>>>(p);    // gamma_h, all t
  gk<M_BETA><<<dim3(4, 512), dim3(256), 0, stream>>>(p);  // beta, all t

  PSP ps{};
  ps.x = (const float*)d_in[0];  ps.mask = (const float*)d_in[1];
  ps.b_hist = (const float*)d_in[8];  ps.b_fr = (const float*)d_in[10];
  ps.b_ih = (const float*)d_in[14];   ps.b_hh = (const float*)d_in[16];
  ps.Whist = Whist; ps.Wfr = Wfr; ps.gammah = gammah; ps.beta = beta;
  ps.Wih8 = Wih8; ps.Whh8 = Whh8; ps.mask8 = mask8;
  ps.hb0 = hb0; ps.hb1 = hb1; ps.h80 = h80; ps.h81 = h81;
  ps.num = num; ps.out = (float*)d_out;
  ps.flags = flags; ps.xcc = xcc;

  (void)hipFuncSetAttribute((const void*)k_loopP,
      hipFuncAttributeMaxDynamicSharedMemorySize, 160640);
  k_loopP<<<dim3(128), dim3(1024), 160640, stream>>>(ps);

  k_final<<<dim3(1), dim3(64), 0, stream>>>(num, den, (float*)d_out);
}

// Round 16
// 4245.057 us; speedup vs baseline: 2.1377x; 1.1510x over previous
//
#include <hip/hip_runtime.h>
#include <hip/hip_bf16.h>

typedef float f32x4 __attribute__((ext_vector_type(4)));
typedef __bf16 bf16x8 __attribute__((ext_vector_type(8)));
typedef short s16x8 __attribute__((ext_vector_type(8)));
typedef unsigned short u16;
typedef unsigned long long u64;
typedef unsigned char u8;

constexpr int Bb = 256, Tt = 128, Ff = 256, Hh = 512;
constexpr int TF = Tt * Ff;                       // 32768
constexpr long OFF_RECON = (long)Bb * Tt * Ff;    // 8388608
constexpr long OFF_H     = 2L * Bb * Tt * Ff;     // 16777216
constexpr long OFF_LOSS  = OFF_H + (long)Bb * Hh; // 16908288

__device__ inline float sigf(float v){ return 1.f / (1.f + expf(-v)); }
__device__ inline u16 f2b(float f){
  unsigned u = __float_as_uint(f);
  u += 0x7fffu + ((u >> 16) & 1u);   // RNE
  return (u16)(u >> 16);
}
__device__ inline float b2f(u16 b){ return __uint_as_float(((unsigned)b) << 16); }

// ---- fp8 e4m3 (OCP) conversion ----
__device__ inline unsigned f2e4_sw(float f){
  unsigned u = __float_as_uint(f);
  unsigned s = (u >> 24) & 0x80u;
  int e = (int)((u >> 23) & 0xff) - 127;
  unsigned m = u & 0x7fffffu;
  if (((u >> 23) & 0xff) == 0xff) return s | 0x7e;
  if (e > 8 || (e == 8 && m > 0x600000)) return s | 0x7e;
  if (e < -10) return s;
  if (e >= -6) {
    unsigned keep = m >> 20, rest = m & 0xfffffu;
    keep += (rest > 0x80000u) || (rest == 0x80000u && (keep & 1));
    unsigned ee = (unsigned)(e + 7);
    if (keep == 8) { keep = 0; ee += 1; }
    if (ee >= 16) return s | 0x7e;
    return s | (ee << 3) | keep;
  }
  unsigned full = (1u << 23) | m;
  int shift = 20 + (-6 - e);
  unsigned keep = full >> shift;
  unsigned rest = full & ((1u << shift) - 1u);
  unsigned half = 1u << (shift - 1);
  keep += (rest > half) || (rest == half && (keep & 1));
  return s | keep;
}
__device__ inline unsigned f2e4(float f){
#if __has_builtin(__builtin_amdgcn_cvt_pk_fp8_f32)
  return (unsigned)__builtin_amdgcn_cvt_pk_fp8_f32(f, f, 0, false) & 0xffu;
#else
  return f2e4_sw(f);
#endif
}
__device__ inline unsigned pk2e4(float a, float b){
#if __has_builtin(__builtin_amdgcn_cvt_pk_fp8_f32)
  return (unsigned)__builtin_amdgcn_cvt_pk_fp8_f32(a, b, 0, false) & 0xffffu;
#else
  return f2e4_sw(a) | (f2e4_sw(b) << 8);
#endif
}

__device__ inline f32x4 mfma16(bf16x8 a, bf16x8 b, f32x4 c){
  return __builtin_amdgcn_mfma_f32_16x16x32_bf16(a, b, c, 0, 0, 0);
}
__device__ inline f32x4 mfma8(u64 a, u64 b, f32x4 c){
  return __builtin_amdgcn_mfma_f32_16x16x32_fp8_fp8((long)a, (long)b, c, 0, 0, 0);
}
__device__ inline bf16x8 ldb8(const u16* p){ return *reinterpret_cast<const bf16x8*>(p); }
__device__ inline bf16x8 cvt8(const float* p){
  const float4 a = ((const float4*)p)[0], b = ((const float4*)p)[1];
  s16x8 r;
  r[0]=f2b(a.x); r[1]=f2b(a.y); r[2]=f2b(a.z); r[3]=f2b(a.w);
  r[4]=f2b(b.x); r[5]=f2b(b.y); r[6]=f2b(b.z); r[7]=f2b(b.w);
  return __builtin_bit_cast(bf16x8, r);
}
// 8 bf16 (LDS) -> 8 fp8 packed in u64
__device__ inline u64 cvt_h8(const u16* hs){
  unsigned lo = pk2e4(b2f(hs[0]), b2f(hs[1])) | (pk2e4(b2f(hs[2]), b2f(hs[3])) << 16);
  unsigned hi = pk2e4(b2f(hs[4]), b2f(hs[5])) | (pk2e4(b2f(hs[6]), b2f(hs[7])) << 16);
  return (u64)lo | ((u64)hi << 32);
}

// ---------------- hoisted big GEMMs (gamma_h, beta for all t; [t][b] layout) ----------------
enum { M_GH, M_BETA };

struct P {
  const float *x, *mask, *deltas;
  const float *b_gh, *w_gx, *b_gx, *b_comb;
  const u16 *Wgh, *Wcomb;
  u16 *gammah, *beta;
};

template<int MODE>
__global__ __launch_bounds__(256) void gk(P p)
{
  constexpr int K = (MODE==M_GH) ? 256 : 512;
  const int lane = threadIdx.x & 63;
  const int w = threadIdx.x >> 6;
  const int m0 = blockIdx.y*64 + (w>>1)*32;
  const int n0 = blockIdx.x*64 + (w&1)*32;
  const int fr = lane & 15;
  const int kg = (lane >> 4) << 3;

  f32x4 acc[2][2] = {};
  for (int k = 0; k < K; k += 32) {
    const int kk = k + kg;
    bf16x8 a[2], b[2];
    #pragma unroll
    for (int r = 0; r < 2; ++r) {
      const int mr = m0 + 16*r + fr;
      if constexpr (MODE == M_GH) {
        a[r] = cvt8(p.deltas + (size_t)mr*256 + kk);
      } else {
        if (kk < 256) {
          const float4 d0 = *(const float4*)(p.deltas + (size_t)mr*256 + kk);
          const float4 d1 = *(const float4*)(p.deltas + (size_t)mr*256 + kk + 4);
          const float4 w0 = *(const float4*)(p.w_gx + kk);
          const float4 w1 = *(const float4*)(p.w_gx + kk + 4);
          const float4 g0 = *(const float4*)(p.b_gx + kk);
          const float4 g1 = *(const float4*)(p.b_gx + kk + 4);
          s16x8 v;
          v[0]=f2b(expf(-fmaxf(d0.x*w0.x+g0.x,0.f)));
          v[1]=f2b(expf(-fmaxf(d0.y*w0.y+g0.y,0.f)));
          v[2]=f2b(expf(-fmaxf(d0.z*w0.z+g0.z,0.f)));
          v[3]=f2b(expf(-fmaxf(d0.w*w0.w+g0.w,0.f)));
          v[4]=f2b(expf(-fmaxf(d1.x*w1.x+g1.x,0.f)));
          v[5]=f2b(expf(-fmaxf(d1.y*w1.y+g1.y,0.f)));
          v[6]=f2b(expf(-fmaxf(d1.z*w1.z+g1.z,0.f)));
          v[7]=f2b(expf(-fmaxf(d1.w*w1.w+g1.w,0.f)));
          a[r] = __builtin_bit_cast(bf16x8, v);
        } else {
          a[r] = cvt8(p.mask + (size_t)mr*256 + (kk-256));
        }
      }
    }
    #pragma unroll
    for (int cc = 0; cc < 2; ++cc) {
      const int nr = n0 + 16*cc + fr;
      if constexpr (MODE == M_GH) b[cc] = ldb8(p.Wgh   + (size_t)nr*256 + kk);
      else                        b[cc] = ldb8(p.Wcomb + (size_t)nr*512 + kk);
    }
    #pragma unroll
    for (int r = 0; r < 2; ++r)
      #pragma unroll
      for (int cc = 0; cc < 2; ++cc)
        acc[r][cc] = mfma16(a[r], b[cc], acc[r][cc]);
  }

  #pragma unroll
  for (int r = 0; r < 2; ++r)
    #pragma unroll
    for (int cc = 0; cc < 2; ++cc)
      #pragma unroll
      for (int q = 0; q < 4; ++q) {
        const int m = m0 + 16*r + (lane>>4)*4 + q;   // m = b*128 + t
        const int n = n0 + 16*cc + (lane&15);
        const size_t tb = (size_t)(m & 127)*256 + (m >> 7);   // [t][b]
        if constexpr (MODE == M_GH) {
          float v = expf(-fmaxf(acc[r][cc][q] + p.b_gh[n], 0.f));
          p.gammah[tb*512 + n] = f2b(v);
        } else {
          float v = sigf(acc[r][cc][q] + p.b_comb[n]);
          p.beta[tb*256 + n] = f2b(v);
        }
      }
}

// ---------------- weight conversion / den / final ----------------
constexpr int CV_TOT = 131072+131072+65536+131072; // bf16 ones
__global__ __launch_bounds__(256) void k_conv(
    const float* Wgh, const float* Whist, const float* Wfr, const float* Wcomb,
    u16* ogh, u16* ohist, u16* ofr, u16* ocomb)
{
  int i = blockIdx.x*256 + threadIdx.x;
  if (i >= CV_TOT) return;
  int j = i;
  if (j < 131072) { ogh[j] = f2b(Wgh[j]); return; }       j -= 131072;
  if (j < 131072) { ohist[j] = f2b(Whist[j]); return; }   j -= 131072;
  if (j < 65536)  { ofr[j] = ((j>>8)==(j&255)) ? (u16)0 : f2b(Wfr[j]); return; } j -= 65536;
  ocomb[j] = f2b(Wcomb[j]);
}

__global__ __launch_bounds__(256) void k_conv8(
    const float* Wih, const float* Whh, u8* oih, u8* ohh)
{
  int i = blockIdx.x*256 + threadIdx.x;   // pair index, total 1048576
  if (i < 524288) {
    ((u16*)oih)[i] = (u16)pk2e4(Wih[2*i], Wih[2*i+1]);
  } else {
    int j = i - 524288;
    ((u16*)ohh)[j] = (u16)pk2e4(Whh[2*j], Whh[2*j+1]);
  }
}

__global__ __launch_bounds__(256) void k_den(const float* __restrict__ mask,
                                             float* den, u8* mask8)
{
  const int t = blockIdx.x;
  const int f = threadIdx.x;
  float s = 0.f;
  for (int b = 0; b < Bb; ++b) {
    float mv = mask[(size_t)b*TF + (size_t)t*256 + f];
    s += mv;
    mask8[((size_t)t*256 + b)*256 + f] = (u8)f2e4(mv);
  }
  __shared__ float red[4];
  #pragma unroll
  for (int o = 32; o; o >>= 1) s += __shfl_down(s, o);
  if ((f & 63) == 0) red[f >> 6] = s;
  __syncthreads();
  if (f == 0) den[t] = red[0]+red[1]+red[2]+red[3];
}

__global__ void k_final(const float* num, const float* den, float* out)
{
  if (threadIdx.x < 64) {
    int t = threadIdx.x;
    float s = num[t]/(den[t]+1e-12f) + num[t+64]/(den[t+64]+1e-12f);
    #pragma unroll
    for (int o = 32; o; o >>= 1) s += __shfl_down(s, o);
    if (t == 0) { out[OFF_LOSS] = s; out[OFF_LOSS+1] = 0.f; }
  }
}

// ---------------- persistent recurrence: 16 slabs x 8 cg-blocks, 1024 thr/block ----------------
struct PSP {
  const float *x, *mask;
  const float *b_hist, *b_fr, *b_ih, *b_hh;
  const u16 *Whist, *Wfr, *gammah, *beta;
  const u8 *Wih8, *Whh8, *mask8;
  u16 *hb0, *hb1;                    // parity double-buffered h (bf16 only)
  float *num, *out;
  unsigned *flags; int *xcc;
};

// slab = bid&15 (16 rows); cg = bid>>4 (64 h-cols). Slab members bid = slab+16j
// all ≡ slab (mod 8). Handoff: plain h stores + vmcnt(0) + relaxed agent flag
// (fast path); release/acquire fallback if runtime XCC check fails (G16-safe).
// Each WAVE polls the flags itself then stages its own h row -> poll overlaps
// h-load, one barrier. fp8 h for Whh derived in-register from LDS h (no h8 buf).
__global__ __launch_bounds__(1024, 4) void k_loopP(PSP p)
{
  __shared__ u16  h_s[16*520];       // 16640 B (bf16 h_dec, row stride 520)
  __shared__ u16  xr_s[16*264];      //  8448 B
  __shared__ u8   ximp_s[16*264];    //  4224 B
  __shared__ float pre_s[4*16*66];   // 16896 B
  __shared__ int s_fast;

  const int tid = threadIdx.x, lane = tid & 63, w = tid >> 6;
  const int fr = lane & 15, kg = (lane >> 4) << 3;
  const int bid = blockIdx.x;
  const int slab = bid & 15, cg = bid >> 4;
  const int m0 = slab*16, hc0 = cg*64;

  // publish XCC id; decide fast (same-XCD slab) path  [r14-proven]
  if (tid == 0) {
    unsigned xv;
    asm volatile("s_getreg_b32 %0, hwreg(HW_REG_XCC_ID)" : "=s"(xv));
    __hip_atomic_store(p.xcc + bid, (int)(xv & 15u) + 1, __ATOMIC_RELAXED, __HIP_MEMORY_SCOPE_AGENT);
    int v0 = 0, ok = 1;
    #pragma unroll 1
    for (int j = 0; j < 8; ++j) {
      int v; unsigned spin = 0;
      do {
        v = __hip_atomic_load(p.xcc + slab + 16*j, __ATOMIC_RELAXED, __HIP_MEMORY_SCOPE_AGENT);
        if (v) break;
        __builtin_amdgcn_s_sleep(8);
      } while (++spin < (1u<<22));
      if (j == 0) v0 = v;
      ok &= (v != 0) && (v == v0);
    }
    s_fast = ok;
  }
  __syncthreads();
  const int fast = s_fast;

  // hoisted per-lane constants
  const int nA0 = w * 16;                   // A-part: wave owns 16 cols
  const float bh  = p.b_hist[nA0 + fr];
  const float bfv = p.b_fr  [nA0 + fr];
  const int gB = w & 3, qh = w >> 2;        // B-part: wave = (gate, col-quarter)
  float bsum[4];
  #pragma unroll
  for (int g = 0; g < 4; ++g)
    bsum[g] = p.b_ih[g*512 + hc0 + lane] + p.b_hh[g*512 + hc0 + lane];
  float c0 = 0.f;

  for (int t = 0; t < Tt; ++t) {
    const u16* hr  = (t & 1) ? p.hb1 : p.hb0;
    u16*       hw  = (t & 1) ? p.hb0 : p.hb1;

    // ===== prefetch recurrence-independent streams (pre-wait) =====
    float mmv[4], xxv[4]; u16 betv[4];
    #pragma unroll
    for (int q = 0; q < 4; ++q) {
      const int row = (lane>>4)*4 + q;
      const int n   = nA0 + fr;
      const size_t gi = (size_t)(m0+row)*TF + (size_t)t*256 + n;
      xxv[q] = p.x[gi];
      mmv[q] = p.mask[gi];
      betv[q] = p.beta[((size_t)t*256 + m0+row)*256 + n];
    }
    u16 gnv = 0;
    if (t < Tt-1)
      gnv = p.gammah[((size_t)(t+1)*256 + m0 + w)*512 + hc0 + lane];

    // ===== each wave polls all 8 slab flags, then stages its own h row =====
    if (t > 0) {
      if (lane < 8) {
        const unsigned tgt = (unsigned)t;
        const unsigned* mf = p.flags + (size_t)(slab + 16*lane)*16;
        unsigned spin = 0;
        if (fast) {
          while (__hip_atomic_load(mf, __ATOMIC_RELAXED, __HIP_MEMORY_SCOPE_AGENT) < tgt
                 && spin < (1u<<24)) { __builtin_amdgcn_s_sleep(2); ++spin; }
        } else {
          while (__hip_atomic_load(mf, __ATOMIC_ACQUIRE, __HIP_MEMORY_SCOPE_AGENT) < tgt
                 && spin < (1u<<24)) { __builtin_amdgcn_s_sleep(2); ++spin; }
        }
      }
      __builtin_amdgcn_sched_barrier(0);
    }
    {
      bf16x8 hv;
      const u16* src = hr + (size_t)(m0 + w)*512 + lane*8;
      asm volatile("global_load_dwordx4 %0, %1, off sc0\n\ts_waitcnt vmcnt(0)"
                   : "=v"(hv) : "v"(src) : "memory");
      *(bf16x8*)(h_s + w*520 + lane*8) = hv;
    }
    __syncthreads();

    // ===== XH: x_h = h @ Whist^T (K=512), h from LDS =====
    f32x4 acc = {};
    #pragma unroll
    for (int k = 0; k < 16; ++k) {
      bf16x8 a = *(const bf16x8*)(h_s + fr*520 + k*32 + kg);
      bf16x8 b = ldb8(p.Whist + (size_t)(nA0 + fr)*512 + k*32 + kg);
      acc = mfma16(a, b, acc);
    }
    float xhv[4];
    #pragma unroll
    for (int q = 0; q < 4; ++q) {
      const int row = (lane>>4)*4 + q;
      const int n   = nA0 + fr;
      const float v = acc[q] + bh;
      xhv[q] = v;
      xr_s[row*264 + n] = f2b(mmv[q]*xxv[q] + (1.f-mmv[q])*v);
    }
    __syncthreads();

    // ===== XU: xu = xr @ Wfr_m^T (K=256) =====
    f32x4 acc2 = {};
    #pragma unroll
    for (int k = 0; k < 8; ++k) {
      bf16x8 a = *(const bf16x8*)(xr_s + fr*264 + k*32 + kg);
      bf16x8 b = ldb8(p.Wfr + (size_t)(nA0 + fr)*256 + k*32 + kg);
      acc2 = mfma16(a, b, acc2);
    }
    float xcv[4], xiv[4], lnum = 0.f;
    #pragma unroll
    for (int q = 0; q < 4; ++q) {
      const int row = (lane>>4)*4 + q;
      const int n   = nA0 + fr;
      const float xu  = acc2[q] + bfv;
      const float bet = b2f(betv[q]);
      const float xc  = bet*xu + (1.f-bet)*xhv[q];
      const float xi  = mmv[q]*xxv[q] + (1.f-mmv[q])*xc;
      ximp_s[row*264 + n] = (u8)f2e4(xi);
      xcv[q] = xc; xiv[q] = xi;
      lnum += fabsf(xc - xxv[q])*mmv[q];
    }
    __syncthreads();   // ximp_s ready

    // ===== B-part: fp8 gates (K=1024); wave = (gate gB, col-quarter qh) =====
    f32x4 ag = {};
    #pragma unroll
    for (int k = 0; k < 8; ++k) {         // K 0..256: x_imp fp8 (LDS)
      const u64 a = *(const u64*)(ximp_s + (size_t)fr*264 + k*32 + kg);
      const u64 b = *(const u64*)(p.Wih8 + (size_t)(gB*512 + hc0 + qh*16 + fr)*512 + k*32 + kg);
      ag = mfma8(a, b, ag);
    }
    #pragma unroll
    for (int k = 0; k < 8; ++k) {         // K 256..512: mask fp8
      const u64 a = *(const u64*)(p.mask8 + ((size_t)t*256 + m0 + fr)*256 + k*32 + kg);
      const u64 b = *(const u64*)(p.Wih8 + (size_t)(gB*512 + hc0 + qh*16 + fr)*512 + 256 + k*32 + kg);
      ag = mfma8(a, b, ag);
    }
    #pragma unroll
    for (int k = 0; k < 16; ++k) {        // K 512..1024: h fp8 from LDS bf16 (cvt)
      const u64 a = cvt_h8(h_s + fr*520 + k*32 + kg);
      const u64 b = *(const u64*)(p.Whh8 + (size_t)(gB*512 + hc0 + qh*16 + fr)*512 + k*32 + kg);
      ag = mfma8(a, b, ag);
    }
    #pragma unroll
    for (int q = 0; q < 4; ++q) {
      const int row = (lane>>4)*4 + q;
      pre_s[(gB*16 + row)*66 + qh*16 + fr] = ag[q];
    }
    __syncthreads();

    // ===== fused LSTM: thread owns exactly (row=w, col=lane) =====
    {
      const float pi = pre_s[(0*16 + w)*66 + lane] + bsum[0];
      const float pf = pre_s[(1*16 + w)*66 + lane] + bsum[1];
      const float pg = pre_s[(2*16 + w)*66 + lane] + bsum[2];
      const float po = pre_s[(3*16 + w)*66 + lane] + bsum[3];
      const float cv = sigf(pf)*c0 + sigf(pi)*tanhf(pg);
      c0 = cv;
      const float hv = sigf(po)*tanhf(cv);
      const int idx = (m0+w)*512 + hc0 + lane;
      if (t == Tt-1) {
        __builtin_nontemporal_store(hv, p.out + OFF_H + idx);
      } else {
        const float hd = hv * b2f(gnv);
        hw[idx] = f2b(hd);                  // plain: write-through to local L2
      }
    }

    // ===== publish step completion (h stores drained first) =====
    if (t < Tt-1) {
      asm volatile("s_waitcnt vmcnt(0)" ::: "memory");
      __syncthreads();
      if (tid == 0) {
        if (fast)
          __hip_atomic_store(p.flags + (size_t)bid*16, (unsigned)(t+1),
                             __ATOMIC_RELAXED, __HIP_MEMORY_SCOPE_AGENT);
        else
          __hip_atomic_store(p.flags + (size_t)bid*16, (unsigned)(t+1),
                             __ATOMIC_RELEASE, __HIP_MEMORY_SCOPE_AGENT);
      }
    }

    // ===== deferred (shadowed by next step's poll): loss + output stores =====
    if (cg == 0) {
      #pragma unroll
      for (int o = 32; o; o >>= 1) lnum += __shfl_down(lnum, o);
      if (lane == 0) atomicAdd(p.num + t, lnum);
      #pragma unroll
      for (int q = 0; q < 4; ++q) {
        const int row = (lane>>4)*4 + q;
        const int n   = nA0 + fr;
        const size_t gi = (size_t)(m0+row)*TF + (size_t)t*256 + n;
        __builtin_nontemporal_store(xcv[q], p.out + OFF_RECON + gi);
        __builtin_nontemporal_store(xiv[q], p.out + gi);
      }
    }
  }
}

extern "C" void kernel_launch(void* const* d_in, const int* in_sizes, int n_in,
                              void* d_out, int out_size, void* d_ws, size_t ws_size,
                              hipStream_t stream)
{
  char* wsb = (char*)d_ws;
  unsigned* flags = (unsigned*)(wsb + 0);        //     8192 (128 x 64B)
  int*      xcc   = (int*)(wsb + 8192);          //      512
  float*    num   = (float*)(wsb + 8704);        //      512
  u16*  hb0    = (u16*)(wsb + 9216);             //   262144  (memset 0..271360)
  u16*  hb1    = (u16*)(wsb + 271360);           //   262144
  float* den   = (float*)(wsb + 533504);         //      512
  u8*   mask8  = (u8*)(wsb + 534016);            //  8388608  [t][b][f]
  u16*  beta   = (u16*)(wsb + 8922624);          // 16777216  [t][b][f]
  u16*  gammah = (u16*)(wsb + 25699840);         // 33554432  [t][b][h]
  u16*  Whist  = (u16*)(wsb + 59254272);         //   262144
  u16*  Wfr    = (u16*)(wsb + 59516416);         //   131072
  u16*  Wgh    = (u16*)(wsb + 59647488);         //   262144
  u16*  Wcomb  = (u16*)(wsb + 59909632);         //   262144
  u8*   Wih8   = (u8*)(wsb + 60171776);          //  1048576
  u8*   Whh8   = (u8*)(wsb + 61220352);          //  1048576  -> 62268928 total

  // zero flags, xcc, num, hb0 on every (graph-replayed) call
  hipMemsetAsync(d_ws, 0, 271360, stream);

  k_conv<<<dim3((CV_TOT+255)/256), dim3(256), 0, stream>>>(
      (const float*)d_in[3], (const float*)d_in[7], (const float*)d_in[9],
      (const float*)d_in[11], Wgh, Whist, Wfr, Wcomb);
  k_conv8<<<dim3(4096), dim3(256), 0, stream>>>(
      (const float*)d_in[13], (const float*)d_in[15], Wih8, Whh8);
  k_den<<<dim3(128), dim3(256), 0, stream>>>((const float*)d_in[1], den, mask8);

  P p{};
  p.x = (const float*)d_in[0];  p.mask = (const float*)d_in[1];
  p.deltas = (const float*)d_in[2];
  p.b_gh = (const float*)d_in[4];  p.w_gx = (const float*)d_in[5];
  p.b_gx = (const float*)d_in[6];  p.b_comb = (const float*)d_in[12];
  p.Wgh = Wgh; p.Wcomb = Wcomb;
  p.gammah = gammah; p.beta = beta;
  gk<M_GH><<<dim3(8, 512), dim3(256), 0, stream>>>(p);    // gamma_h, all t
  gk<M_BETA><<<dim3(4, 512), dim3(256), 0, stream>>>(p);  // beta, all t

  PSP ps{};
  ps.x = (const float*)d_in[0];  ps.mask = (const float*)d_in[1];
  ps.b_hist = (const float*)d_in[8];  ps.b_fr = (const float*)d_in[10];
  ps.b_ih = (const float*)d_in[14];   ps.b_hh = (const float*)d_in[16];
  ps.Whist = Whist; ps.Wfr = Wfr; ps.gammah = gammah; ps.beta = beta;
  ps.Wih8 = Wih8; ps.Whh8 = Whh8; ps.mask8 = mask8;
  ps.hb0 = hb0; ps.hb1 = hb1;
  ps.num = num; ps.out = (float*)d_out;
  ps.flags = flags; ps.xcc = xcc;
  k_loopP<<<dim3(128), dim3(1024), 0, stream>>>(ps);

  k_final<<<dim3(1), dim3(64), 0, stream>>>(num, den, (float*)d_out);
}